// Round 1
// baseline (667.063 us; speedup 1.0000x reference)
//
#include <hip/hip_runtime.h>
#include <hip/hip_bf16.h>
#include <math.h>

#define NN 50000
#define NE 800000

__device__ __forceinline__ float lrelu(float x) { return x >= 0.f ? x : 0.2f * x; }

__device__ __forceinline__ void fma4(float4& acc, float a, const float4& b) {
  acc.x = fmaf(a, b.x, acc.x);
  acc.y = fmaf(a, b.y, acc.y);
  acc.z = fmaf(a, b.z, acc.z);
  acc.w = fmaf(a, b.w, acc.w);
}

// ---------------- CSR build (dst-indexed) ----------------
__global__ void count_kernel(const int* __restrict__ ei, int* __restrict__ counts, int E) {
  int e = blockIdx.x * blockDim.x + threadIdx.x;
  if (e < E) atomicAdd(&counts[ei[E + e]], 1);
}

__global__ __launch_bounds__(1024) void scan_kernel(const int* __restrict__ counts,
                                                    int* __restrict__ row_ptr, int n) {
  __shared__ int part[1024];
  int tid = threadIdx.x;
  int per = (n + 1023) / 1024;
  int beg = tid * per;
  int end = min(beg + per, n);
  int sum = 0;
  for (int i = beg; i < end; ++i) sum += counts[i];
  part[tid] = sum;
  __syncthreads();
  for (int off = 1; off < 1024; off <<= 1) {
    int v = (tid >= off) ? part[tid - off] : 0;
    __syncthreads();
    part[tid] += v;
    __syncthreads();
  }
  int run = (tid == 0) ? 0 : part[tid - 1];
  for (int i = beg; i < end; ++i) { row_ptr[i] = run; run += counts[i]; }
  if (tid == 1023) row_ptr[n] = part[1023];
}

__global__ void fill_kernel(const int* __restrict__ ei, const int* __restrict__ row_ptr,
                            int* __restrict__ cursor, int* __restrict__ col_src, int E) {
  int e = blockIdx.x * blockDim.x + threadIdx.x;
  if (e < E) {
    int d = ei[E + e];
    int pos = row_ptr[d] + atomicAdd(&cursor[d], 1);
    col_src[pos] = ei[e];
  }
}

// ---------------- f32 tiled GEMM: out[n,NC] = A[n,K] @ B[K,NC] (+bias)(+relu) ----------------
template <int K, int NC>
__global__ __launch_bounds__(256) void gemm_kernel(const float* __restrict__ A,
                                                   const float* __restrict__ B,
                                                   const float* __restrict__ bias, int do_relu,
                                                   float* __restrict__ out, int n) {
  constexpr int CG = NC / 4;   // col groups of 4
  constexpr int RG = 256 / CG; // row groups of 4
  constexpr int ROWS = RG * 4;
  constexpr int KT = K / 32;

  __shared__ __align__(16) float xs[ROWS][36];
  __shared__ __align__(16) float ws[32][NC];

  const int tid = threadIdx.x;
  const int tc = tid % CG;
  const int tr = tid / CG;
  const int row0 = blockIdx.x * ROWS;

  float4 acc0 = make_float4(0, 0, 0, 0);
  float4 acc1 = acc0, acc2 = acc0, acc3 = acc0;

  for (int kt = 0; kt < KT; ++kt) {
    const int k0 = kt * 32;
    for (int idx = tid; idx < ROWS * 8; idx += 256) {
      int r = idx >> 3, c4 = (idx & 7) * 4;
      float4 v = make_float4(0, 0, 0, 0);
      if (row0 + r < n) v = *(const float4*)&A[(size_t)(row0 + r) * K + k0 + c4];
      *(float4*)&xs[r][c4] = v;
    }
    for (int idx = tid; idx < 8 * NC; idx += 256) {
      int kr = idx / CG, c4 = (idx % CG) * 4;
      *(float4*)&ws[kr][c4] = *(const float4*)&B[(size_t)(k0 + kr) * NC + c4];
    }
    __syncthreads();
#pragma unroll
    for (int kk = 0; kk < 32; kk += 4) {
      float4 a0 = *(const float4*)&xs[tr * 4 + 0][kk];
      float4 a1 = *(const float4*)&xs[tr * 4 + 1][kk];
      float4 a2 = *(const float4*)&xs[tr * 4 + 2][kk];
      float4 a3 = *(const float4*)&xs[tr * 4 + 3][kk];
      const float* f0 = (const float*)&a0;
      const float* f1 = (const float*)&a1;
      const float* f2 = (const float*)&a2;
      const float* f3 = (const float*)&a3;
#pragma unroll
      for (int q = 0; q < 4; ++q) {
        float4 b = *(const float4*)&ws[kk + q][tc * 4];
        fma4(acc0, f0[q], b);
        fma4(acc1, f1[q], b);
        fma4(acc2, f2[q], b);
        fma4(acc3, f3[q], b);
      }
    }
    __syncthreads();
  }

  float4 bv = make_float4(0, 0, 0, 0);
  if (bias) bv = *(const float4*)&bias[tc * 4];
  float4 accs[4] = {acc0, acc1, acc2, acc3};
#pragma unroll
  for (int i = 0; i < 4; ++i) {
    int row = row0 + tr * 4 + i;
    if (row < n) {
      float4 v = accs[i];
      v.x += bv.x; v.y += bv.y; v.z += bv.z; v.w += bv.w;
      if (do_relu) {
        v.x = fmaxf(v.x, 0.f); v.y = fmaxf(v.y, 0.f);
        v.z = fmaxf(v.z, 0.f); v.w = fmaxf(v.w, 0.f);
      }
      *(float4*)&out[(size_t)row * NC + tc * 4] = v;
    }
  }
}

// ---------------- per-node attention scores ----------------
__global__ __launch_bounds__(256) void att2_kernel(const float* __restrict__ h,
                                                   const float* __restrict__ a_src,
                                                   const float* __restrict__ a_dst,
                                                   float* __restrict__ s, float* __restrict__ t,
                                                   int n) {
  int wid = (blockIdx.x * 256 + threadIdx.x) >> 6;
  int lane = threadIdx.x & 63;
  if (wid >= n) return;
  float h0 = h[(size_t)wid * 128 + lane];
  float h1 = h[(size_t)wid * 128 + 64 + lane];
  float v0 = h0 * a_src[lane];
  float v1 = h1 * a_src[64 + lane];
  float v2 = h0 * a_dst[lane];
  float v3 = h1 * a_dst[64 + lane];
#pragma unroll
  for (int off = 32; off > 0; off >>= 1) {
    v0 += __shfl_xor(v0, off);
    v1 += __shfl_xor(v1, off);
    v2 += __shfl_xor(v2, off);
    v3 += __shfl_xor(v3, off);
  }
  if (lane == 0) {
    s[wid * 2 + 0] = v0;
    s[wid * 2 + 1] = v1;
    t[wid * 2 + 0] = v2;
    t[wid * 2 + 1] = v3;
  }
}

__global__ __launch_bounds__(256) void att1_kernel(const float* __restrict__ h,
                                                   const float* __restrict__ a_src,
                                                   const float* __restrict__ a_dst,
                                                   float* __restrict__ s, float* __restrict__ t,
                                                   int n) {
  int wid = (blockIdx.x * 256 + threadIdx.x) >> 6;
  int lane = threadIdx.x & 63;
  if (wid >= n) return;
  float h0 = h[(size_t)wid * 64 + lane];
  float v0 = h0 * a_src[lane];
  float v1 = h0 * a_dst[lane];
#pragma unroll
  for (int off = 32; off > 0; off >>= 1) {
    v0 += __shfl_xor(v0, off);
    v1 += __shfl_xor(v1, off);
  }
  if (lane == 0) {
    s[wid] = v0;
    t[wid] = v1;
  }
}

// ---------------- per-node online-softmax aggregation, H=2, C=64 ----------------
__global__ __launch_bounds__(256) void agg2_kernel(const float* __restrict__ h,
                                                   const float* __restrict__ s,
                                                   const float* __restrict__ t,
                                                   const int* __restrict__ row_ptr,
                                                   const int* __restrict__ col_src,
                                                   const float* __restrict__ bias,
                                                   float* __restrict__ out, int n, int do_relu) {
  int wid = (blockIdx.x * 256 + threadIdx.x) >> 6;
  int lane = threadIdx.x & 63;
  if (wid >= n) return;
  const int node = wid;
  const float t0 = t[node * 2 + 0];
  const float t1 = t[node * 2 + 1];
  // implicit self loop first
  float m0 = lrelu(s[node * 2 + 0] + t0);
  float m1 = lrelu(s[node * 2 + 1] + t1);
  float d0 = 1.f, d1 = 1.f;
  float acc0 = h[(size_t)node * 128 + lane];
  float acc1 = h[(size_t)node * 128 + 64 + lane];
  const int beg = row_ptr[node], end = row_ptr[node + 1];
  for (int i = beg; i < end; ++i) {
    int srcn = col_src[i];
    float e0 = lrelu(s[srcn * 2 + 0] + t0);
    float e1 = lrelu(s[srcn * 2 + 1] + t1);
    if (e0 > m0) {
      float sc = __expf(m0 - e0);
      d0 *= sc; acc0 *= sc; m0 = e0;
    }
    if (e1 > m1) {
      float sc = __expf(m1 - e1);
      d1 *= sc; acc1 *= sc; m1 = e1;
    }
    float p0 = __expf(e0 - m0);
    float p1 = __expf(e1 - m1);
    d0 += p0;
    d1 += p1;
    acc0 = fmaf(p0, h[(size_t)srcn * 128 + lane], acc0);
    acc1 = fmaf(p1, h[(size_t)srcn * 128 + 64 + lane], acc1);
  }
  float o0 = acc0 / (d0 + 1e-16f) + bias[lane];
  float o1 = acc1 / (d1 + 1e-16f) + bias[64 + lane];
  if (do_relu) {
    o0 = fmaxf(o0, 0.f);
    o1 = fmaxf(o1, 0.f);
  }
  out[(size_t)node * 128 + lane] = o0;
  out[(size_t)node * 128 + 64 + lane] = o1;
}

// ---------------- per-node aggregation, H=1, C=64 (layer 2, no relu) ----------------
__global__ __launch_bounds__(256) void agg1_kernel(const float* __restrict__ h,
                                                   const float* __restrict__ s,
                                                   const float* __restrict__ t,
                                                   const int* __restrict__ row_ptr,
                                                   const int* __restrict__ col_src,
                                                   const float* __restrict__ bias,
                                                   float* __restrict__ out, int n) {
  int wid = (blockIdx.x * 256 + threadIdx.x) >> 6;
  int lane = threadIdx.x & 63;
  if (wid >= n) return;
  const int node = wid;
  const float t0 = t[node];
  float m0 = lrelu(s[node] + t0);
  float d0 = 1.f;
  float acc0 = h[(size_t)node * 64 + lane];
  const int beg = row_ptr[node], end = row_ptr[node + 1];
  for (int i = beg; i < end; ++i) {
    int srcn = col_src[i];
    float e0 = lrelu(s[srcn] + t0);
    if (e0 > m0) {
      float sc = __expf(m0 - e0);
      d0 *= sc; acc0 *= sc; m0 = e0;
    }
    float p0 = __expf(e0 - m0);
    d0 += p0;
    acc0 = fmaf(p0, h[(size_t)srcn * 64 + lane], acc0);
  }
  out[(size_t)node * 64 + lane] = acc0 / (d0 + 1e-16f) + bias[lane];
}

extern "C" void kernel_launch(void* const* d_in, const int* in_sizes, int n_in,
                              void* d_out, int out_size, void* d_ws, size_t ws_size,
                              hipStream_t stream) {
  const float* x       = (const float*)d_in[0];
  const int*   ei      = (const int*)d_in[1];
  const float* W0      = (const float*)d_in[2];
  const float* a_src0  = (const float*)d_in[3];
  const float* a_dst0  = (const float*)d_in[4];
  const float* b0      = (const float*)d_in[5];
  const float* W1      = (const float*)d_in[6];
  const float* a_src1  = (const float*)d_in[7];
  const float* a_dst1  = (const float*)d_in[8];
  const float* b1      = (const float*)d_in[9];
  const float* W2      = (const float*)d_in[10];
  const float* a_src2  = (const float*)d_in[11];
  const float* a_dst2  = (const float*)d_in[12];
  const float* b2      = (const float*)d_in[13];
  const float* Wv      = (const float*)d_in[14];
  const float* bv      = (const float*)d_in[15];
  const float* Wt      = (const float*)d_in[16];
  const float* bt      = (const float*)d_in[17];

  const int n = NN, E = NE;

  // workspace carve-up (16B aligned chunks)
  char* w = (char*)d_ws;
  int* counts  = (int*)w;  w += (size_t)n * 4;          // 200000 B
  int* row_ptr = (int*)w;  w += (size_t)(n + 4) * 4;    // 200016 B
  int* cursor  = (int*)w;  w += (size_t)n * 4;
  int* col_src = (int*)w;  w += (size_t)E * 4;          // 3.2 MB
  float* s_buf = (float*)w; w += (size_t)n * 2 * 4;
  float* t_buf = (float*)w; w += (size_t)n * 2 * 4;
  float* bufA  = (float*)w; w += (size_t)n * 128 * 4;   // 25.6 MB
  float* bufB  = (float*)w; w += (size_t)n * 128 * 4;   // 25.6 MB

  float* out_h = (float*)d_out;            // [N,64]
  float* out_v = out_h + (size_t)n * 64;   // [N,64]
  float* out_t = out_v + (size_t)n * 64;   // [N,64]

  // ---- CSR build ----
  hipMemsetAsync(counts, 0, (size_t)n * 4, stream);
  hipMemsetAsync(cursor, 0, (size_t)n * 4, stream);
  count_kernel<<<(E + 255) / 256, 256, 0, stream>>>(ei, counts, E);
  scan_kernel<<<1, 1024, 0, stream>>>(counts, row_ptr, n);
  fill_kernel<<<(E + 255) / 256, 256, 0, stream>>>(ei, row_ptr, cursor, col_src, E);

  const int wgrid = (n + 3) / 4; // one wave per node, 4 waves per block

  // ---- layer 0: x[N,512] @ W0 -> bufA[N,128]; att; aggregate -> bufB ----
  gemm_kernel<512, 128><<<(n + 31) / 32, 256, 0, stream>>>(x, W0, nullptr, 0, bufA, n);
  att2_kernel<<<wgrid, 256, 0, stream>>>(bufA, a_src0, a_dst0, s_buf, t_buf, n);
  agg2_kernel<<<wgrid, 256, 0, stream>>>(bufA, s_buf, t_buf, row_ptr, col_src, b0, bufB, n, 1);

  // ---- layer 1: bufB @ W1 -> bufA; att; aggregate -> bufB ----
  gemm_kernel<128, 128><<<(n + 31) / 32, 256, 0, stream>>>(bufB, W1, nullptr, 0, bufA, n);
  att2_kernel<<<wgrid, 256, 0, stream>>>(bufA, a_src1, a_dst1, s_buf, t_buf, n);
  agg2_kernel<<<wgrid, 256, 0, stream>>>(bufA, s_buf, t_buf, row_ptr, col_src, b1, bufB, n, 1);

  // ---- layer 2: bufB @ W2 -> bufA[N,64]; att; aggregate -> d_out[0:N*64] ----
  gemm_kernel<128, 64><<<(n + 63) / 64, 256, 0, stream>>>(bufB, W2, nullptr, 0, bufA, n);
  att1_kernel<<<wgrid, 256, 0, stream>>>(bufA, a_src2, a_dst2, s_buf, t_buf, n);
  agg1_kernel<<<wgrid, 256, 0, stream>>>(bufA, s_buf, t_buf, row_ptr, col_src, b2, out_h, n);

  // ---- MLP heads ----
  gemm_kernel<64, 64><<<(n + 63) / 64, 256, 0, stream>>>(out_h, Wv, bv, 1, out_v, n);
  gemm_kernel<64, 64><<<(n + 63) / 64, 256, 0, stream>>>(out_h, Wt, bt, 1, out_t, n);
}

// Round 2
// 601.974 us; speedup vs baseline: 1.1081x; 1.1081x over previous
//
#include <hip/hip_runtime.h>
#include <hip/hip_bf16.h>
#include <math.h>

#define NN 50000
#define NE 800000

__device__ __forceinline__ float lrelu(float x) { return x >= 0.f ? x : 0.2f * x; }

__device__ __forceinline__ void fma4(float4& acc, float a, const float4& b) {
  acc.x = fmaf(a, b.x, acc.x);
  acc.y = fmaf(a, b.y, acc.y);
  acc.z = fmaf(a, b.z, acc.z);
  acc.w = fmaf(a, b.w, acc.w);
}

// ---------------- CSR build (dst-indexed) ----------------
__global__ void count_kernel(const int* __restrict__ ei, int* __restrict__ counts, int E) {
  int e = blockIdx.x * blockDim.x + threadIdx.x;
  if (e < E) atomicAdd(&counts[ei[E + e]], 1);
}

__global__ __launch_bounds__(1024) void scan_kernel(const int* __restrict__ counts,
                                                    int* __restrict__ row_ptr, int n) {
  __shared__ int part[1024];
  int tid = threadIdx.x;
  int per = (n + 1023) / 1024;
  int beg = tid * per;
  int end = min(beg + per, n);
  int sum = 0;
  for (int i = beg; i < end; ++i) sum += counts[i];
  part[tid] = sum;
  __syncthreads();
  for (int off = 1; off < 1024; off <<= 1) {
    int v = (tid >= off) ? part[tid - off] : 0;
    __syncthreads();
    part[tid] += v;
    __syncthreads();
  }
  int run = (tid == 0) ? 0 : part[tid - 1];
  for (int i = beg; i < end; ++i) { row_ptr[i] = run; run += counts[i]; }
  if (tid == 1023) row_ptr[n] = part[1023];
}

__global__ void fill_kernel(const int* __restrict__ ei, const int* __restrict__ row_ptr,
                            int* __restrict__ cursor, int* __restrict__ col_src, int E) {
  int e = blockIdx.x * blockDim.x + threadIdx.x;
  if (e < E) {
    int d = ei[E + e];
    int pos = row_ptr[d] + atomicAdd(&cursor[d], 1);
    col_src[pos] = ei[e];
  }
}

// ---------------- f32 tiled GEMM (generic, used for NC=64 cases) ----------------
template <int K, int NC>
__global__ __launch_bounds__(256) void gemm_kernel(const float* __restrict__ A,
                                                   const float* __restrict__ B,
                                                   const float* __restrict__ bias, int do_relu,
                                                   float* __restrict__ out, int n) {
  constexpr int CG = NC / 4;   // col groups of 4
  constexpr int RG = 256 / CG; // row groups of 4
  constexpr int ROWS = RG * 4;
  constexpr int KT = K / 32;

  __shared__ __align__(16) float xs[ROWS][36];
  __shared__ __align__(16) float ws[32][NC];

  const int tid = threadIdx.x;
  const int tc = tid % CG;
  const int tr = tid / CG;
  const int row0 = blockIdx.x * ROWS;

  float4 acc0 = make_float4(0, 0, 0, 0);
  float4 acc1 = acc0, acc2 = acc0, acc3 = acc0;

  for (int kt = 0; kt < KT; ++kt) {
    const int k0 = kt * 32;
    for (int idx = tid; idx < ROWS * 8; idx += 256) {
      int r = idx >> 3, c4 = (idx & 7) * 4;
      float4 v = make_float4(0, 0, 0, 0);
      if (row0 + r < n) v = *(const float4*)&A[(size_t)(row0 + r) * K + k0 + c4];
      *(float4*)&xs[r][c4] = v;
    }
    for (int idx = tid; idx < 8 * NC; idx += 256) {
      int kr = idx / CG, c4 = (idx % CG) * 4;
      *(float4*)&ws[kr][c4] = *(const float4*)&B[(size_t)(k0 + kr) * NC + c4];
    }
    __syncthreads();
#pragma unroll
    for (int kk = 0; kk < 32; kk += 4) {
      float4 a0 = *(const float4*)&xs[tr * 4 + 0][kk];
      float4 a1 = *(const float4*)&xs[tr * 4 + 1][kk];
      float4 a2 = *(const float4*)&xs[tr * 4 + 2][kk];
      float4 a3 = *(const float4*)&xs[tr * 4 + 3][kk];
      const float* f0 = (const float*)&a0;
      const float* f1 = (const float*)&a1;
      const float* f2 = (const float*)&a2;
      const float* f3 = (const float*)&a3;
#pragma unroll
      for (int q = 0; q < 4; ++q) {
        float4 b = *(const float4*)&ws[kk + q][tc * 4];
        fma4(acc0, f0[q], b);
        fma4(acc1, f1[q], b);
        fma4(acc2, f2[q], b);
        fma4(acc3, f3[q], b);
      }
    }
    __syncthreads();
  }

  float4 bv = make_float4(0, 0, 0, 0);
  if (bias) bv = *(const float4*)&bias[tc * 4];
  float4 accs[4] = {acc0, acc1, acc2, acc3};
#pragma unroll
  for (int i = 0; i < 4; ++i) {
    int row = row0 + tr * 4 + i;
    if (row < n) {
      float4 v = accs[i];
      v.x += bv.x; v.y += bv.y; v.z += bv.z; v.w += bv.w;
      if (do_relu) {
        v.x = fmaxf(v.x, 0.f); v.y = fmaxf(v.y, 0.f);
        v.z = fmaxf(v.z, 0.f); v.w = fmaxf(v.w, 0.f);
      }
      *(float4*)&out[(size_t)row * NC + tc * 4] = v;
    }
  }
}

// ---------------- f32 GEMM, 128x128 tile, 8x8 per-thread regs (NC=128) ----------------
template <int K>
__global__ __launch_bounds__(256) void gemm128_kernel(const float* __restrict__ A,
                                                      const float* __restrict__ B,
                                                      float* __restrict__ out, int n) {
  // xs4[kq][row] holds A[row][k0+kq*4 .. +3] as float4 (k-major float4 => b128 staging, no transpose)
  __shared__ __align__(16) float4 xs4[8][128];  // 16 KB
  __shared__ __align__(16) float ws[32][128];   // 16 KB

  const int tid = threadIdx.x;
  const int tc = tid & 15;   // col group (0..15)
  const int tr = tid >> 4;   // row group (0..15)
  const int row0 = blockIdx.x * 128;

  float4 acc[2][2][4];  // [row half][col half][row-in-quad], each float4 = 4 cols
#pragma unroll
  for (int a = 0; a < 2; ++a)
#pragma unroll
    for (int b = 0; b < 2; ++b)
#pragma unroll
      for (int i = 0; i < 4; ++i) acc[a][b][i] = make_float4(0, 0, 0, 0);

  for (int kt = 0; kt < K / 32; ++kt) {
    const int k0 = kt * 32;
#pragma unroll
    for (int j = 0; j < 4; ++j) {
      int idx = tid + j * 256;       // 1024 float4s = 128 rows x 8 kq
      int r = idx >> 3, kq = idx & 7;
      float4 v = make_float4(0, 0, 0, 0);
      if (row0 + r < n) v = *(const float4*)&A[(size_t)(row0 + r) * K + k0 + kq * 4];
      xs4[kq][r] = v;
    }
#pragma unroll
    for (int j = 0; j < 4; ++j) {
      int idx = tid + j * 256;       // 1024 float4s = 32 k-rows x 32 col-quads
      int kr = idx >> 5, c4 = (idx & 31) * 4;
      *(float4*)&ws[kr][c4] = *(const float4*)&B[(size_t)(k0 + kr) * 128 + c4];
    }
    __syncthreads();
#pragma unroll
    for (int kq = 0; kq < 8; ++kq) {
      float4 alo[4], ahi[4];
#pragma unroll
      for (int i = 0; i < 4; ++i) {
        alo[i] = xs4[kq][tr * 4 + i];        // broadcast across 16 lanes
        ahi[i] = xs4[kq][64 + tr * 4 + i];
      }
#pragma unroll
      for (int kk = 0; kk < 4; ++kk) {
        float4 blo = *(const float4*)&ws[kq * 4 + kk][tc * 4];
        float4 bhi = *(const float4*)&ws[kq * 4 + kk][64 + tc * 4];
#pragma unroll
        for (int i = 0; i < 4; ++i) {
          float a0 = ((const float*)&alo[i])[kk];
          float a1 = ((const float*)&ahi[i])[kk];
          fma4(acc[0][0][i], a0, blo);
          fma4(acc[0][1][i], a0, bhi);
          fma4(acc[1][0][i], a1, blo);
          fma4(acc[1][1][i], a1, bhi);
        }
      }
    }
    __syncthreads();
  }

#pragma unroll
  for (int a = 0; a < 2; ++a)
#pragma unroll
    for (int i = 0; i < 4; ++i) {
      int row = row0 + a * 64 + tr * 4 + i;
      if (row < n) {
        *(float4*)&out[(size_t)row * 128 + tc * 4] = acc[a][0][i];
        *(float4*)&out[(size_t)row * 128 + 64 + tc * 4] = acc[a][1][i];
      }
    }
}

// ---------------- per-node attention scores ----------------
__global__ __launch_bounds__(256) void att2_kernel(const float* __restrict__ h,
                                                   const float* __restrict__ a_src,
                                                   const float* __restrict__ a_dst,
                                                   float* __restrict__ s, float* __restrict__ t,
                                                   int n) {
  int wid = (blockIdx.x * 256 + threadIdx.x) >> 6;
  int lane = threadIdx.x & 63;
  if (wid >= n) return;
  float h0 = h[(size_t)wid * 128 + lane];
  float h1 = h[(size_t)wid * 128 + 64 + lane];
  float v0 = h0 * a_src[lane];
  float v1 = h1 * a_src[64 + lane];
  float v2 = h0 * a_dst[lane];
  float v3 = h1 * a_dst[64 + lane];
#pragma unroll
  for (int off = 32; off > 0; off >>= 1) {
    v0 += __shfl_xor(v0, off);
    v1 += __shfl_xor(v1, off);
    v2 += __shfl_xor(v2, off);
    v3 += __shfl_xor(v3, off);
  }
  if (lane == 0) {
    s[wid * 2 + 0] = v0;
    s[wid * 2 + 1] = v1;
    t[wid * 2 + 0] = v2;
    t[wid * 2 + 1] = v3;
  }
}

__global__ __launch_bounds__(256) void att1_kernel(const float* __restrict__ h,
                                                   const float* __restrict__ a_src,
                                                   const float* __restrict__ a_dst,
                                                   float* __restrict__ s, float* __restrict__ t,
                                                   int n) {
  int wid = (blockIdx.x * 256 + threadIdx.x) >> 6;
  int lane = threadIdx.x & 63;
  if (wid >= n) return;
  float h0 = h[(size_t)wid * 64 + lane];
  float v0 = h0 * a_src[lane];
  float v1 = h0 * a_dst[lane];
#pragma unroll
  for (int off = 32; off > 0; off >>= 1) {
    v0 += __shfl_xor(v0, off);
    v1 += __shfl_xor(v1, off);
  }
  if (lane == 0) {
    s[wid] = v0;
    t[wid] = v1;
  }
}

// ---------------- two-pass softmax aggregation, H=2, C=64 ----------------
// Pass A: lane-parallel max over incoming edges (+self). Pass B: 64-edge chunks,
// lane-parallel exp, then uniform j-loop broadcasting (src, p) via shfl; every
// lane does coalesced h-gathers + fma. No loop-carried rescale dependency.
__global__ __launch_bounds__(256) void agg2_kernel(const float* __restrict__ h,
                                                   const float2* __restrict__ s2,
                                                   const float* __restrict__ t,
                                                   const int* __restrict__ row_ptr,
                                                   const int* __restrict__ col_src,
                                                   const float* __restrict__ bias,
                                                   float* __restrict__ out, int n, int do_relu) {
  int wid = (blockIdx.x * 256 + threadIdx.x) >> 6;
  int lane = threadIdx.x & 63;
  if (wid >= n) return;
  const int node = wid;
  const float t0 = t[node * 2 + 0];
  const float t1 = t[node * 2 + 1];
  const int beg = row_ptr[node], end = row_ptr[node + 1];

  // pass A: max (self loop included)
  float2 sself = s2[node];
  const float e_self0 = lrelu(sself.x + t0);
  const float e_self1 = lrelu(sself.y + t1);
  float m0 = e_self0, m1 = e_self1;
  for (int i = beg + lane; i < end; i += 64) {
    float2 sv = s2[col_src[i]];
    m0 = fmaxf(m0, lrelu(sv.x + t0));
    m1 = fmaxf(m1, lrelu(sv.y + t1));
  }
#pragma unroll
  for (int off = 32; off > 0; off >>= 1) {
    m0 = fmaxf(m0, __shfl_xor(m0, off));
    m1 = fmaxf(m1, __shfl_xor(m1, off));
  }

  // self contribution
  float p0 = __expf(e_self0 - m0);
  float p1 = __expf(e_self1 - m1);
  float d0 = p0, d1 = p1;
  float acc0 = p0 * h[(size_t)node * 128 + lane];
  float acc1 = p1 * h[(size_t)node * 128 + 64 + lane];

  // pass B: chunks of 64 edges
  for (int base = beg; base < end; base += 64) {
    int i = base + lane;
    int srcn = 0;
    float q0 = 0.f, q1 = 0.f;
    if (i < end) {
      srcn = col_src[i];
      float2 sv = s2[srcn];
      q0 = __expf(lrelu(sv.x + t0) - m0);
      q1 = __expf(lrelu(sv.y + t1) - m1);
    }
    const int cnt = min(64, end - base);
    for (int j = 0; j < cnt; ++j) {
      int sj = __shfl(srcn, j);
      float pj0 = __shfl(q0, j);
      float pj1 = __shfl(q1, j);
      d0 += pj0;
      d1 += pj1;
      acc0 = fmaf(pj0, h[(size_t)sj * 128 + lane], acc0);
      acc1 = fmaf(pj1, h[(size_t)sj * 128 + 64 + lane], acc1);
    }
  }

  float o0 = acc0 / (d0 + 1e-16f) + bias[lane];
  float o1 = acc1 / (d1 + 1e-16f) + bias[64 + lane];
  if (do_relu) {
    o0 = fmaxf(o0, 0.f);
    o1 = fmaxf(o1, 0.f);
  }
  out[(size_t)node * 128 + lane] = o0;
  out[(size_t)node * 128 + 64 + lane] = o1;
}

// ---------------- two-pass softmax aggregation, H=1, C=64 ----------------
__global__ __launch_bounds__(256) void agg1_kernel(const float* __restrict__ h,
                                                   const float* __restrict__ s,
                                                   const float* __restrict__ t,
                                                   const int* __restrict__ row_ptr,
                                                   const int* __restrict__ col_src,
                                                   const float* __restrict__ bias,
                                                   float* __restrict__ out, int n) {
  int wid = (blockIdx.x * 256 + threadIdx.x) >> 6;
  int lane = threadIdx.x & 63;
  if (wid >= n) return;
  const int node = wid;
  const float t0 = t[node];
  const int beg = row_ptr[node], end = row_ptr[node + 1];

  const float e_self = lrelu(s[node] + t0);
  float m0 = e_self;
  for (int i = beg + lane; i < end; i += 64) {
    m0 = fmaxf(m0, lrelu(s[col_src[i]] + t0));
  }
#pragma unroll
  for (int off = 32; off > 0; off >>= 1) m0 = fmaxf(m0, __shfl_xor(m0, off));

  float p = __expf(e_self - m0);
  float d0 = p;
  float acc0 = p * h[(size_t)node * 64 + lane];

  for (int base = beg; base < end; base += 64) {
    int i = base + lane;
    int srcn = 0;
    float q0 = 0.f;
    if (i < end) {
      srcn = col_src[i];
      q0 = __expf(lrelu(s[srcn] + t0) - m0);
    }
    const int cnt = min(64, end - base);
    for (int j = 0; j < cnt; ++j) {
      int sj = __shfl(srcn, j);
      float pj = __shfl(q0, j);
      d0 += pj;
      acc0 = fmaf(pj, h[(size_t)sj * 64 + lane], acc0);
    }
  }
  out[(size_t)node * 64 + lane] = acc0 / (d0 + 1e-16f) + bias[lane];
}

extern "C" void kernel_launch(void* const* d_in, const int* in_sizes, int n_in,
                              void* d_out, int out_size, void* d_ws, size_t ws_size,
                              hipStream_t stream) {
  const float* x       = (const float*)d_in[0];
  const int*   ei      = (const int*)d_in[1];
  const float* W0      = (const float*)d_in[2];
  const float* a_src0  = (const float*)d_in[3];
  const float* a_dst0  = (const float*)d_in[4];
  const float* b0      = (const float*)d_in[5];
  const float* W1      = (const float*)d_in[6];
  const float* a_src1  = (const float*)d_in[7];
  const float* a_dst1  = (const float*)d_in[8];
  const float* b1      = (const float*)d_in[9];
  const float* W2      = (const float*)d_in[10];
  const float* a_src2  = (const float*)d_in[11];
  const float* a_dst2  = (const float*)d_in[12];
  const float* b2      = (const float*)d_in[13];
  const float* Wv      = (const float*)d_in[14];
  const float* bv      = (const float*)d_in[15];
  const float* Wt      = (const float*)d_in[16];
  const float* bt      = (const float*)d_in[17];

  const int n = NN, E = NE;

  char* w = (char*)d_ws;
  int* counts  = (int*)w;  w += (size_t)n * 4;
  int* row_ptr = (int*)w;  w += (size_t)(n + 4) * 4;
  int* cursor  = (int*)w;  w += (size_t)n * 4;
  int* col_src = (int*)w;  w += (size_t)E * 4;
  float* s_buf = (float*)w; w += (size_t)n * 2 * 4;
  float* t_buf = (float*)w; w += (size_t)n * 2 * 4;
  float* bufA  = (float*)w; w += (size_t)n * 128 * 4;
  float* bufB  = (float*)w; w += (size_t)n * 128 * 4;

  float* out_h = (float*)d_out;
  float* out_v = out_h + (size_t)n * 64;
  float* out_t = out_v + (size_t)n * 64;

  // ---- CSR build ----
  hipMemsetAsync(counts, 0, (size_t)n * 4, stream);
  hipMemsetAsync(cursor, 0, (size_t)n * 4, stream);
  count_kernel<<<(E + 255) / 256, 256, 0, stream>>>(ei, counts, E);
  scan_kernel<<<1, 1024, 0, stream>>>(counts, row_ptr, n);
  fill_kernel<<<(E + 255) / 256, 256, 0, stream>>>(ei, row_ptr, cursor, col_src, E);

  const int wgrid = (n + 3) / 4;       // one wave per node
  const int g128 = (n + 127) / 128;    // gemm128 grid

  // ---- layer 0 ----
  gemm128_kernel<512><<<g128, 256, 0, stream>>>(x, W0, bufA, n);
  att2_kernel<<<wgrid, 256, 0, stream>>>(bufA, a_src0, a_dst0, s_buf, t_buf, n);
  agg2_kernel<<<wgrid, 256, 0, stream>>>(bufA, (const float2*)s_buf, t_buf, row_ptr, col_src,
                                         b0, bufB, n, 1);

  // ---- layer 1 ----
  gemm128_kernel<128><<<g128, 256, 0, stream>>>(bufB, W1, bufA, n);
  att2_kernel<<<wgrid, 256, 0, stream>>>(bufA, a_src1, a_dst1, s_buf, t_buf, n);
  agg2_kernel<<<wgrid, 256, 0, stream>>>(bufA, (const float2*)s_buf, t_buf, row_ptr, col_src,
                                         b1, bufB, n, 1);

  // ---- layer 2 ----
  gemm_kernel<128, 64><<<(n + 63) / 64, 256, 0, stream>>>(bufB, W2, nullptr, 0, bufA, n);
  att1_kernel<<<wgrid, 256, 0, stream>>>(bufA, a_src2, a_dst2, s_buf, t_buf, n);
  agg1_kernel<<<wgrid, 256, 0, stream>>>(bufA, s_buf, t_buf, row_ptr, col_src, b2, out_h, n);

  // ---- MLP heads ----
  gemm_kernel<64, 64><<<(n + 63) / 64, 256, 0, stream>>>(out_h, Wv, bv, 1, out_v, n);
  gemm_kernel<64, 64><<<(n + 63) / 64, 256, 0, stream>>>(out_h, Wt, bt, 1, out_t, n);
}

// Round 3
// 570.305 us; speedup vs baseline: 1.1697x; 1.0555x over previous
//
#include <hip/hip_runtime.h>
#include <hip/hip_bf16.h>
#include <math.h>

#define NN 50000
#define NE 800000

__device__ __forceinline__ float lrelu(float x) { return x >= 0.f ? x : 0.2f * x; }

__device__ __forceinline__ void fma4(float4& acc, float a, const float4& b) {
  acc.x = fmaf(a, b.x, acc.x);
  acc.y = fmaf(a, b.y, acc.y);
  acc.z = fmaf(a, b.z, acc.z);
  acc.w = fmaf(a, b.w, acc.w);
}

// ---------------- CSR build (dst-indexed) ----------------
__global__ void count_kernel(const int* __restrict__ ei, int* __restrict__ counts, int E) {
  int e = blockIdx.x * blockDim.x + threadIdx.x;
  if (e < E) atomicAdd(&counts[ei[E + e]], 1);
}

__global__ __launch_bounds__(1024) void scan_kernel(const int* __restrict__ counts,
                                                    int* __restrict__ row_ptr, int n) {
  __shared__ int part[1024];
  int tid = threadIdx.x;
  int per = (n + 1023) / 1024;
  int beg = tid * per;
  int end = min(beg + per, n);
  int sum = 0;
  for (int i = beg; i < end; ++i) sum += counts[i];
  part[tid] = sum;
  __syncthreads();
  for (int off = 1; off < 1024; off <<= 1) {
    int v = (tid >= off) ? part[tid - off] : 0;
    __syncthreads();
    part[tid] += v;
    __syncthreads();
  }
  int run = (tid == 0) ? 0 : part[tid - 1];
  for (int i = beg; i < end; ++i) { row_ptr[i] = run; run += counts[i]; }
  if (tid == 1023) row_ptr[n] = part[1023];
}

__global__ void fill_kernel(const int* __restrict__ ei, const int* __restrict__ row_ptr,
                            int* __restrict__ cursor, int* __restrict__ col_src, int E) {
  int e = blockIdx.x * blockDim.x + threadIdx.x;
  if (e < E) {
    int d = ei[E + e];
    int pos = row_ptr[d] + atomicAdd(&cursor[d], 1);
    col_src[pos] = ei[e];
  }
}

// ---------------- f32 tiled GEMM (generic, NC=64 cases) ----------------
template <int K, int NC>
__global__ __launch_bounds__(256) void gemm_kernel(const float* __restrict__ A,
                                                   const float* __restrict__ B,
                                                   const float* __restrict__ bias, int do_relu,
                                                   float* __restrict__ out, int n) {
  constexpr int CG = NC / 4;
  constexpr int RG = 256 / CG;
  constexpr int ROWS = RG * 4;
  constexpr int KT = K / 32;

  __shared__ __align__(16) float xs[ROWS][36];
  __shared__ __align__(16) float ws[32][NC];

  const int tid = threadIdx.x;
  const int tc = tid % CG;
  const int tr = tid / CG;
  const int row0 = blockIdx.x * ROWS;

  float4 acc0 = make_float4(0, 0, 0, 0);
  float4 acc1 = acc0, acc2 = acc0, acc3 = acc0;

  for (int kt = 0; kt < KT; ++kt) {
    const int k0 = kt * 32;
    for (int idx = tid; idx < ROWS * 8; idx += 256) {
      int r = idx >> 3, c4 = (idx & 7) * 4;
      float4 v = make_float4(0, 0, 0, 0);
      if (row0 + r < n) v = *(const float4*)&A[(size_t)(row0 + r) * K + k0 + c4];
      *(float4*)&xs[r][c4] = v;
    }
    for (int idx = tid; idx < 8 * NC; idx += 256) {
      int kr = idx / CG, c4 = (idx % CG) * 4;
      *(float4*)&ws[kr][c4] = *(const float4*)&B[(size_t)(k0 + kr) * NC + c4];
    }
    __syncthreads();
#pragma unroll
    for (int kk = 0; kk < 32; kk += 4) {
      float4 a0 = *(const float4*)&xs[tr * 4 + 0][kk];
      float4 a1 = *(const float4*)&xs[tr * 4 + 1][kk];
      float4 a2 = *(const float4*)&xs[tr * 4 + 2][kk];
      float4 a3 = *(const float4*)&xs[tr * 4 + 3][kk];
      const float* f0 = (const float*)&a0;
      const float* f1 = (const float*)&a1;
      const float* f2 = (const float*)&a2;
      const float* f3 = (const float*)&a3;
#pragma unroll
      for (int q = 0; q < 4; ++q) {
        float4 b = *(const float4*)&ws[kk + q][tc * 4];
        fma4(acc0, f0[q], b);
        fma4(acc1, f1[q], b);
        fma4(acc2, f2[q], b);
        fma4(acc3, f3[q], b);
      }
    }
    __syncthreads();
  }

  float4 bv = make_float4(0, 0, 0, 0);
  if (bias) bv = *(const float4*)&bias[tc * 4];
  float4 accs[4] = {acc0, acc1, acc2, acc3};
#pragma unroll
  for (int i = 0; i < 4; ++i) {
    int row = row0 + tr * 4 + i;
    if (row < n) {
      float4 v = accs[i];
      v.x += bv.x; v.y += bv.y; v.z += bv.z; v.w += bv.w;
      if (do_relu) {
        v.x = fmaxf(v.x, 0.f); v.y = fmaxf(v.y, 0.f);
        v.z = fmaxf(v.z, 0.f); v.w = fmaxf(v.w, 0.f);
      }
      *(float4*)&out[(size_t)row * NC + tc * 4] = v;
    }
  }
}

// ---------------- f32 GEMM, 128x128 tile, 8x8/thread, split-K over blockIdx.y ----------------
template <int KLEN>
__global__ __launch_bounds__(256) void gemm128s_kernel(const float* __restrict__ A, int kstride,
                                                       const float* __restrict__ B,
                                                       float* __restrict__ out, int n) {
  __shared__ __align__(16) float4 xs4[8][129];  // padded: staging writes conflict-free
  __shared__ __align__(16) float ws[32][128];

  const int tid = threadIdx.x;
  const int tc = tid & 15;
  const int tr = tid >> 4;
  const int row0 = blockIdx.x * 128;
  const int k0base = blockIdx.y * KLEN;
  out += (size_t)blockIdx.y * n * 128;

  float4 acc[2][2][4];
#pragma unroll
  for (int a = 0; a < 2; ++a)
#pragma unroll
    for (int b = 0; b < 2; ++b)
#pragma unroll
      for (int i = 0; i < 4; ++i) acc[a][b][i] = make_float4(0, 0, 0, 0);

  for (int kt = 0; kt < KLEN / 32; ++kt) {
    const int k0 = k0base + kt * 32;
#pragma unroll
    for (int j = 0; j < 4; ++j) {
      int idx = tid + j * 256;
      int r = idx >> 3, kq = idx & 7;
      float4 v = make_float4(0, 0, 0, 0);
      if (row0 + r < n) v = *(const float4*)&A[(size_t)(row0 + r) * kstride + k0 + kq * 4];
      xs4[kq][r] = v;
    }
#pragma unroll
    for (int j = 0; j < 4; ++j) {
      int idx = tid + j * 256;
      int kr = idx >> 5, c4 = (idx & 31) * 4;
      *(float4*)&ws[kr][c4] = *(const float4*)&B[(size_t)(k0 + kr) * 128 + c4];
    }
    __syncthreads();
#pragma unroll
    for (int kq = 0; kq < 8; ++kq) {
      float4 alo[4], ahi[4];
#pragma unroll
      for (int i = 0; i < 4; ++i) {
        alo[i] = xs4[kq][tr * 4 + i];
        ahi[i] = xs4[kq][64 + tr * 4 + i];
      }
#pragma unroll
      for (int kk = 0; kk < 4; ++kk) {
        float4 blo = *(const float4*)&ws[kq * 4 + kk][tc * 4];
        float4 bhi = *(const float4*)&ws[kq * 4 + kk][64 + tc * 4];
#pragma unroll
        for (int i = 0; i < 4; ++i) {
          float a0 = ((const float*)&alo[i])[kk];
          float a1 = ((const float*)&ahi[i])[kk];
          fma4(acc[0][0][i], a0, blo);
          fma4(acc[0][1][i], a0, bhi);
          fma4(acc[1][0][i], a1, blo);
          fma4(acc[1][1][i], a1, bhi);
        }
      }
    }
    __syncthreads();
  }

#pragma unroll
  for (int a = 0; a < 2; ++a)
#pragma unroll
    for (int i = 0; i < 4; ++i) {
      int row = row0 + a * 64 + tr * 4 + i;
      if (row < n) {
        *(float4*)&out[(size_t)row * 128 + tc * 4] = acc[a][0][i];
        *(float4*)&out[(size_t)row * 128 + 64 + tc * 4] = acc[a][1][i];
      }
    }
}

// ---------------- combine split-K partials + attention scores + interleave h ----------------
__global__ __launch_bounds__(256) void comb_att2_kernel(const float* __restrict__ P0,
                                                        const float* __restrict__ P1, int nsplit,
                                                        const float* __restrict__ a_src,
                                                        const float* __restrict__ a_dst,
                                                        float2* __restrict__ h2,
                                                        float2* __restrict__ s2,
                                                        float2* __restrict__ t2, int n) {
  int wid = (blockIdx.x * 256 + threadIdx.x) >> 6;
  int lane = threadIdx.x & 63;
  if (wid >= n) return;
  float h0 = P0[(size_t)wid * 128 + lane];
  float h1 = P0[(size_t)wid * 128 + 64 + lane];
  if (nsplit == 2) {
    h0 += P1[(size_t)wid * 128 + lane];
    h1 += P1[(size_t)wid * 128 + 64 + lane];
  }
  h2[(size_t)wid * 64 + lane] = make_float2(h0, h1);
  float v0 = h0 * a_src[lane];
  float v1 = h1 * a_src[64 + lane];
  float v2 = h0 * a_dst[lane];
  float v3 = h1 * a_dst[64 + lane];
#pragma unroll
  for (int off = 32; off > 0; off >>= 1) {
    v0 += __shfl_xor(v0, off);
    v1 += __shfl_xor(v1, off);
    v2 += __shfl_xor(v2, off);
    v3 += __shfl_xor(v3, off);
  }
  if (lane == 0) {
    s2[wid] = make_float2(v0, v1);
    t2[wid] = make_float2(v2, v3);
  }
}

__global__ __launch_bounds__(256) void att1_kernel(const float* __restrict__ h,
                                                   const float* __restrict__ a_src,
                                                   const float* __restrict__ a_dst,
                                                   float* __restrict__ s, float* __restrict__ t,
                                                   int n) {
  int wid = (blockIdx.x * 256 + threadIdx.x) >> 6;
  int lane = threadIdx.x & 63;
  if (wid >= n) return;
  float h0 = h[(size_t)wid * 64 + lane];
  float v0 = h0 * a_src[lane];
  float v1 = h0 * a_dst[lane];
#pragma unroll
  for (int off = 32; off > 0; off >>= 1) {
    v0 += __shfl_xor(v0, off);
    v1 += __shfl_xor(v1, off);
  }
  if (lane == 0) {
    s[wid] = v0;
    t[wid] = v1;
  }
}

// ---------------- two-pass softmax aggregation, H=2, gathers from interleaved h2 ----------------
__global__ __launch_bounds__(256) void agg2_kernel(const float2* __restrict__ h2,
                                                   const float2* __restrict__ s2,
                                                   const float2* __restrict__ t2,
                                                   const int* __restrict__ row_ptr,
                                                   const int* __restrict__ col_src,
                                                   const float* __restrict__ bias,
                                                   float* __restrict__ out, int n, int do_relu) {
  int wid = (blockIdx.x * 256 + threadIdx.x) >> 6;
  int lane = threadIdx.x & 63;
  if (wid >= n) return;
  const int node = wid;
  const float2 tt = t2[node];
  const float t0 = tt.x, t1 = tt.y;
  const int beg = row_ptr[node], end = row_ptr[node + 1];

  // pass A: max (self loop included)
  float2 sself = s2[node];
  const float e_self0 = lrelu(sself.x + t0);
  const float e_self1 = lrelu(sself.y + t1);
  float m0 = e_self0, m1 = e_self1;
  for (int i = beg + lane; i < end; i += 64) {
    float2 sv = s2[col_src[i]];
    m0 = fmaxf(m0, lrelu(sv.x + t0));
    m1 = fmaxf(m1, lrelu(sv.y + t1));
  }
#pragma unroll
  for (int off = 32; off > 0; off >>= 1) {
    m0 = fmaxf(m0, __shfl_xor(m0, off));
    m1 = fmaxf(m1, __shfl_xor(m1, off));
  }

  // self contribution
  float p0 = __expf(e_self0 - m0);
  float p1 = __expf(e_self1 - m1);
  float d0 = p0, d1 = p1;
  float2 hself = h2[(size_t)node * 64 + lane];
  float acc0 = p0 * hself.x;
  float acc1 = p1 * hself.y;

  // pass B: 64-edge chunks, 4-deep prefetch with named registers
  for (int base = beg; base < end; base += 64) {
    int i = base + lane;
    int srcn = node;
    float q0 = 0.f, q1 = 0.f;
    if (i < end) {
      srcn = col_src[i];
      float2 sv = s2[srcn];
      q0 = __expf(lrelu(sv.x + t0) - m0);
      q1 = __expf(lrelu(sv.y + t1) - m1);
    }
    const int cnt = min(64, end - base);
    const int cnt4 = (cnt + 3) & ~3;
    int i0 = __shfl(srcn, 0), i1 = __shfl(srcn, 1), i2 = __shfl(srcn, 2), i3 = __shfl(srcn, 3);
    float2 b0 = h2[(size_t)i0 * 64 + lane];
    float2 b1 = h2[(size_t)i1 * 64 + lane];
    float2 b2 = h2[(size_t)i2 * 64 + lane];
    float2 b3 = h2[(size_t)i3 * 64 + lane];
    for (int j = 0; j < cnt4; j += 4) {
      float p00 = __shfl(q0, j),     p01 = __shfl(q1, j);
      float p10 = __shfl(q0, j + 1), p11 = __shfl(q1, j + 1);
      float p20 = __shfl(q0, j + 2), p21 = __shfl(q1, j + 2);
      float p30 = __shfl(q0, j + 3), p31 = __shfl(q1, j + 3);
      float2 c0 = b0, c1 = b1, c2 = b2, c3 = b3;
      if (j + 4 < cnt4) {
        int n0 = __shfl(srcn, j + 4), n1 = __shfl(srcn, j + 5);
        int n2 = __shfl(srcn, j + 6), n3 = __shfl(srcn, j + 7);
        b0 = h2[(size_t)n0 * 64 + lane];
        b1 = h2[(size_t)n1 * 64 + lane];
        b2 = h2[(size_t)n2 * 64 + lane];
        b3 = h2[(size_t)n3 * 64 + lane];
      }
      d0 += p00 + p10 + p20 + p30;
      d1 += p01 + p11 + p21 + p31;
      acc0 = fmaf(p00, c0.x, acc0);
      acc1 = fmaf(p01, c0.y, acc1);
      acc0 = fmaf(p10, c1.x, acc0);
      acc1 = fmaf(p11, c1.y, acc1);
      acc0 = fmaf(p20, c2.x, acc0);
      acc1 = fmaf(p21, c2.y, acc1);
      acc0 = fmaf(p30, c3.x, acc0);
      acc1 = fmaf(p31, c3.y, acc1);
    }
  }

  float o0 = acc0 / (d0 + 1e-16f) + bias[lane];
  float o1 = acc1 / (d1 + 1e-16f) + bias[64 + lane];
  if (do_relu) {
    o0 = fmaxf(o0, 0.f);
    o1 = fmaxf(o1, 0.f);
  }
  out[(size_t)node * 128 + lane] = o0;
  out[(size_t)node * 128 + 64 + lane] = o1;
}

// ---------------- two-pass softmax aggregation, H=1, C=64 ----------------
__global__ __launch_bounds__(256) void agg1_kernel(const float* __restrict__ h,
                                                   const float* __restrict__ s,
                                                   const float* __restrict__ t,
                                                   const int* __restrict__ row_ptr,
                                                   const int* __restrict__ col_src,
                                                   const float* __restrict__ bias,
                                                   float* __restrict__ out, int n) {
  int wid = (blockIdx.x * 256 + threadIdx.x) >> 6;
  int lane = threadIdx.x & 63;
  if (wid >= n) return;
  const int node = wid;
  const float t0 = t[node];
  const int beg = row_ptr[node], end = row_ptr[node + 1];

  const float e_self = lrelu(s[node] + t0);
  float m0 = e_self;
  for (int i = beg + lane; i < end; i += 64) {
    m0 = fmaxf(m0, lrelu(s[col_src[i]] + t0));
  }
#pragma unroll
  for (int off = 32; off > 0; off >>= 1) m0 = fmaxf(m0, __shfl_xor(m0, off));

  float p = __expf(e_self - m0);
  float d0 = p;
  float acc0 = p * h[(size_t)node * 64 + lane];

  for (int base = beg; base < end; base += 64) {
    int i = base + lane;
    int srcn = node;
    float q0 = 0.f;
    if (i < end) {
      srcn = col_src[i];
      q0 = __expf(lrelu(s[srcn] + t0) - m0);
    }
    const int cnt = min(64, end - base);
    const int cnt4 = (cnt + 3) & ~3;
    int i0 = __shfl(srcn, 0), i1 = __shfl(srcn, 1), i2 = __shfl(srcn, 2), i3 = __shfl(srcn, 3);
    float b0 = h[(size_t)i0 * 64 + lane];
    float b1 = h[(size_t)i1 * 64 + lane];
    float b2 = h[(size_t)i2 * 64 + lane];
    float b3 = h[(size_t)i3 * 64 + lane];
    for (int j = 0; j < cnt4; j += 4) {
      float p0 = __shfl(q0, j),     p1 = __shfl(q0, j + 1);
      float p2 = __shfl(q0, j + 2), p3 = __shfl(q0, j + 3);
      float c0 = b0, c1 = b1, c2 = b2, c3 = b3;
      if (j + 4 < cnt4) {
        int n0 = __shfl(srcn, j + 4), n1 = __shfl(srcn, j + 5);
        int n2 = __shfl(srcn, j + 6), n3 = __shfl(srcn, j + 7);
        b0 = h[(size_t)n0 * 64 + lane];
        b1 = h[(size_t)n1 * 64 + lane];
        b2 = h[(size_t)n2 * 64 + lane];
        b3 = h[(size_t)n3 * 64 + lane];
      }
      d0 += p0 + p1 + p2 + p3;
      acc0 = fmaf(p0, c0, acc0);
      acc0 = fmaf(p1, c1, acc0);
      acc0 = fmaf(p2, c2, acc0);
      acc0 = fmaf(p3, c3, acc0);
    }
  }
  out[(size_t)node * 64 + lane] = acc0 / (d0 + 1e-16f) + bias[lane];
}

extern "C" void kernel_launch(void* const* d_in, const int* in_sizes, int n_in,
                              void* d_out, int out_size, void* d_ws, size_t ws_size,
                              hipStream_t stream) {
  const float* x       = (const float*)d_in[0];
  const int*   ei      = (const int*)d_in[1];
  const float* W0      = (const float*)d_in[2];
  const float* a_src0  = (const float*)d_in[3];
  const float* a_dst0  = (const float*)d_in[4];
  const float* b0      = (const float*)d_in[5];
  const float* W1      = (const float*)d_in[6];
  const float* a_src1  = (const float*)d_in[7];
  const float* a_dst1  = (const float*)d_in[8];
  const float* b1      = (const float*)d_in[9];
  const float* W2      = (const float*)d_in[10];
  const float* a_src2  = (const float*)d_in[11];
  const float* a_dst2  = (const float*)d_in[12];
  const float* b2      = (const float*)d_in[13];
  const float* Wv      = (const float*)d_in[14];
  const float* bv      = (const float*)d_in[15];
  const float* Wt      = (const float*)d_in[16];
  const float* bt      = (const float*)d_in[17];

  const int n = NN, E = NE;

  char* w = (char*)d_ws;
  int* counts  = (int*)w;   w += (size_t)n * 4;
  int* row_ptr = (int*)w;   w += (size_t)(n + 4) * 4;
  int* cursor  = (int*)w;   w += (size_t)n * 4;
  int* col_src = (int*)w;   w += (size_t)E * 4;
  float2* s2   = (float2*)w; w += (size_t)n * 8;
  float2* t2   = (float2*)w; w += (size_t)n * 8;
  float* Abuf  = (float*)w;  w += (size_t)n * 128 * 4;   // 25.6 MB
  float2* h2   = (float2*)w; w += (size_t)n * 64 * 8;    // 25.6 MB
  float* P0    = (float*)w;  w += (size_t)n * 128 * 4;   // 25.6 MB
  // P1 only if workspace allows split-K
  size_t used = (size_t)(w - (char*)d_ws);
  int nsplit = (ws_size >= used + (size_t)n * 128 * 4) ? 2 : 1;
  float* P1 = (float*)w;  // valid only when nsplit==2

  float* hbuf = (float*)h2;          // layer-2 h [N,64] reuses h2 region
  float* s1   = (float*)s2;          // layer-2 scalar s,t reuse s2/t2
  float* t1   = (float*)t2;

  float* out_h = (float*)d_out;
  float* out_v = out_h + (size_t)n * 64;
  float* out_t = out_v + (size_t)n * 64;

  // ---- CSR build ----
  hipMemsetAsync(counts, 0, (size_t)n * 4, stream);
  hipMemsetAsync(cursor, 0, (size_t)n * 4, stream);
  count_kernel<<<(E + 255) / 256, 256, 0, stream>>>(ei, counts, E);
  scan_kernel<<<1, 1024, 0, stream>>>(counts, row_ptr, n);
  fill_kernel<<<(E + 255) / 256, 256, 0, stream>>>(ei, row_ptr, cursor, col_src, E);

  const int wgrid = (n + 3) / 4;
  const dim3 gs(( n + 127) / 128, nsplit);

  // ---- layer 0: x[N,512] @ W0 ----
  if (nsplit == 2)
    gemm128s_kernel<256><<<gs, 256, 0, stream>>>(x, 512, W0, P0, n);
  else
    gemm128s_kernel<512><<<gs, 256, 0, stream>>>(x, 512, W0, P0, n);
  comb_att2_kernel<<<wgrid, 256, 0, stream>>>(P0, P1, nsplit, a_src0, a_dst0, h2, s2, t2, n);
  agg2_kernel<<<wgrid, 256, 0, stream>>>(h2, s2, t2, row_ptr, col_src, b0, Abuf, n, 1);

  // ---- layer 1: Abuf[N,128] @ W1 ----
  if (nsplit == 2)
    gemm128s_kernel<64><<<gs, 256, 0, stream>>>(Abuf, 128, W1, P0, n);
  else
    gemm128s_kernel<128><<<gs, 256, 0, stream>>>(Abuf, 128, W1, P0, n);
  comb_att2_kernel<<<wgrid, 256, 0, stream>>>(P0, P1, nsplit, a_src1, a_dst1, h2, s2, t2, n);
  agg2_kernel<<<wgrid, 256, 0, stream>>>(h2, s2, t2, row_ptr, col_src, b1, Abuf, n, 1);

  // ---- layer 2: Abuf[N,128] @ W2 -> hbuf[N,64] ----
  gemm_kernel<128, 64><<<(n + 63) / 64, 256, 0, stream>>>(Abuf, W2, nullptr, 0, hbuf, n);
  att1_kernel<<<wgrid, 256, 0, stream>>>(hbuf, a_src2, a_dst2, s1, t1, n);
  agg1_kernel<<<wgrid, 256, 0, stream>>>(hbuf, s1, t1, row_ptr, col_src, b2, out_h, n);

  // ---- MLP heads ----
  gemm_kernel<64, 64><<<(n + 63) / 64, 256, 0, stream>>>(out_h, Wv, bv, 1, out_v, n);
  gemm_kernel<64, 64><<<(n + 63) / 64, 256, 0, stream>>>(out_h, Wt, bt, 1, out_t, n);
}

// Round 4
// 495.784 us; speedup vs baseline: 1.3455x; 1.1503x over previous
//
#include <hip/hip_runtime.h>
#include <hip/hip_bf16.h>
#include <math.h>

#define NN 50000
#define NE 800000

typedef unsigned short ushort_t;
typedef unsigned int uint_t;
typedef __attribute__((ext_vector_type(8))) short bf16x8;
typedef __attribute__((ext_vector_type(4))) float f32x4;

__device__ __forceinline__ float lrelu(float x) { return x >= 0.f ? x : 0.2f * x; }

__device__ __forceinline__ ushort_t f2bf_rn(float f) {
  uint_t u = __builtin_bit_cast(uint_t, f);
  uint_t r = u + 0x7FFFu + ((u >> 16) & 1u);
  return (ushort_t)(r >> 16);
}
__device__ __forceinline__ float bf2f(ushort_t h) {
  uint_t u = ((uint_t)h) << 16;
  return __builtin_bit_cast(float, u);
}

__device__ __forceinline__ void fma4(float4& acc, float a, const float4& b) {
  acc.x = fmaf(a, b.x, acc.x);
  acc.y = fmaf(a, b.y, acc.y);
  acc.z = fmaf(a, b.z, acc.z);
  acc.w = fmaf(a, b.w, acc.w);
}

// ---------------- CSR build (dst-indexed) ----------------
__global__ void count_kernel(const int* __restrict__ ei, int* __restrict__ counts, int E) {
  int e = blockIdx.x * blockDim.x + threadIdx.x;
  if (e < E) atomicAdd(&counts[ei[E + e]], 1);
}

__global__ __launch_bounds__(1024) void scan_kernel(const int* __restrict__ counts,
                                                    int* __restrict__ row_ptr, int n) {
  __shared__ int part[1024];
  int tid = threadIdx.x;
  int per = (n + 1023) / 1024;
  int beg = tid * per;
  int end = min(beg + per, n);
  int sum = 0;
  for (int i = beg; i < end; ++i) sum += counts[i];
  part[tid] = sum;
  __syncthreads();
  for (int off = 1; off < 1024; off <<= 1) {
    int v = (tid >= off) ? part[tid - off] : 0;
    __syncthreads();
    part[tid] += v;
    __syncthreads();
  }
  int run = (tid == 0) ? 0 : part[tid - 1];
  for (int i = beg; i < end; ++i) { row_ptr[i] = run; run += counts[i]; }
  if (tid == 1023) row_ptr[n] = part[1023];
}

__global__ void fill_kernel(const int* __restrict__ ei, const int* __restrict__ row_ptr,
                            int* __restrict__ cursor, int* __restrict__ col_src, int E) {
  int e = blockIdx.x * blockDim.x + threadIdx.x;
  if (e < E) {
    int d = ei[E + e];
    int pos = row_ptr[d] + atomicAdd(&cursor[d], 1);
    col_src[pos] = ei[e];
  }
}

// ---------------- W prep: transpose + bf16 hi/lo split. W[K][C] -> wt[C][K] ----------------
__global__ void prep_wt_kernel(const float* __restrict__ W, int Kdim, int C,
                               ushort_t* __restrict__ wth, ushort_t* __restrict__ wtl) {
  int t = blockIdx.x * blockDim.x + threadIdx.x;
  int nk = Kdim >> 4;
  if (t >= C * nk) return;
  int c = t / nk, kc = (t % nk) << 4;
  uint_t hw[8], lw[8];
#pragma unroll
  for (int i = 0; i < 8; ++i) {
    float f0 = W[(size_t)(kc + 2 * i) * C + c];
    float f1 = W[(size_t)(kc + 2 * i + 1) * C + c];
    ushort_t h0 = f2bf_rn(f0), h1 = f2bf_rn(f1);
    ushort_t l0 = f2bf_rn(f0 - bf2f(h0)), l1 = f2bf_rn(f1 - bf2f(h1));
    hw[i] = (uint_t)h0 | ((uint_t)h1 << 16);
    lw[i] = (uint_t)l0 | ((uint_t)l1 << 16);
  }
  uint_t* ph = (uint_t*)&wth[(size_t)c * Kdim + kc];
  uint_t* pl = (uint_t*)&wtl[(size_t)c * Kdim + kc];
  *(uint4*)ph = make_uint4(hw[0], hw[1], hw[2], hw[3]);
  *(uint4*)(ph + 4) = make_uint4(hw[4], hw[5], hw[6], hw[7]);
  *(uint4*)pl = make_uint4(lw[0], lw[1], lw[2], lw[3]);
  *(uint4*)(pl + 4) = make_uint4(lw[4], lw[5], lw[6], lw[7]);
}

// ---------------- MFMA GEMM: out[n,128] = A[n,K]f32 @ W[K,128] via bf16 3-term split ----------------
// A split in-register at staging; W pre-split/transposed (wt[C=128][K] bf16 hi/lo).
// LDS tiles stored [row][k] and [col][k]; both frags read with identical pattern, so the
// MFMA-internal k-slot mapping cancels (permutation-invariant).
template <int K>
__global__ __launch_bounds__(256, 2) void gemm_mfma_kernel(const float* __restrict__ A,
                                                           const ushort_t* __restrict__ wth,
                                                           const ushort_t* __restrict__ wtl,
                                                           float* __restrict__ out, int n) {
  __shared__ __align__(16) ushort_t ah[128][40];
  __shared__ __align__(16) ushort_t al[128][40];
  __shared__ __align__(16) ushort_t bh[128][40];
  __shared__ __align__(16) ushort_t bl[128][40];

  const int t = threadIdx.x;
  const int row0 = blockIdx.x * 128;
  const int srow = t >> 1;          // staging row/col 0..127
  const int skq = (t & 1) * 16;     // staging k offset 0/16

  const int lane = t & 63;
  const int wid = t >> 6;
  const int wm = wid >> 1, wn = wid & 1;
  const int r16 = lane & 15, g = lane >> 4;

  f32x4 acc[4][4];
#pragma unroll
  for (int i = 0; i < 4; ++i)
#pragma unroll
    for (int j = 0; j < 4; ++j) acc[i][j] = (f32x4)(0.f);

  for (int kt = 0; kt < K / 32; ++kt) {
    const int k0 = kt * 32;
    // ---- stage A (split to hi/lo) ----
    {
      uint_t hw[8], lw[8];
      if (row0 + srow < n) {
        const float* ap = &A[(size_t)(row0 + srow) * K + k0 + skq];
#pragma unroll
        for (int j = 0; j < 4; ++j) {
          float4 v = *(const float4*)(ap + j * 4);
          ushort_t h0 = f2bf_rn(v.x), h1 = f2bf_rn(v.y), h2 = f2bf_rn(v.z), h3 = f2bf_rn(v.w);
          ushort_t l0 = f2bf_rn(v.x - bf2f(h0)), l1 = f2bf_rn(v.y - bf2f(h1));
          ushort_t l2 = f2bf_rn(v.z - bf2f(h2)), l3 = f2bf_rn(v.w - bf2f(h3));
          hw[j * 2] = (uint_t)h0 | ((uint_t)h1 << 16);
          hw[j * 2 + 1] = (uint_t)h2 | ((uint_t)h3 << 16);
          lw[j * 2] = (uint_t)l0 | ((uint_t)l1 << 16);
          lw[j * 2 + 1] = (uint_t)l2 | ((uint_t)l3 << 16);
        }
      } else {
#pragma unroll
        for (int j = 0; j < 8; ++j) { hw[j] = 0; lw[j] = 0; }
      }
      *(uint4*)&ah[srow][skq] = make_uint4(hw[0], hw[1], hw[2], hw[3]);
      *(uint4*)&ah[srow][skq + 8] = make_uint4(hw[4], hw[5], hw[6], hw[7]);
      *(uint4*)&al[srow][skq] = make_uint4(lw[0], lw[1], lw[2], lw[3]);
      *(uint4*)&al[srow][skq + 8] = make_uint4(lw[4], lw[5], lw[6], lw[7]);
    }
    // ---- stage W (already bf16 split, transposed) ----
    {
      const ushort_t* ph = &wth[(size_t)srow * K + k0 + skq];
      const ushort_t* pl = &wtl[(size_t)srow * K + k0 + skq];
      uint4 vh0 = *(const uint4*)ph;
      uint4 vh1 = *(const uint4*)(ph + 8);
      uint4 vl0 = *(const uint4*)pl;
      uint4 vl1 = *(const uint4*)(pl + 8);
      *(uint4*)&bh[srow][skq] = vh0;
      *(uint4*)&bh[srow][skq + 8] = vh1;
      *(uint4*)&bl[srow][skq] = vl0;
      *(uint4*)&bl[srow][skq + 8] = vl1;
    }
    __syncthreads();

    bf16x8 fah[4], fal[4], fbh[4], fbl[4];
#pragma unroll
    for (int mf = 0; mf < 4; ++mf) {
      fah[mf] = *(const bf16x8*)&ah[wm * 64 + mf * 16 + r16][g * 8];
      fal[mf] = *(const bf16x8*)&al[wm * 64 + mf * 16 + r16][g * 8];
    }
#pragma unroll
    for (int nf = 0; nf < 4; ++nf) {
      fbh[nf] = *(const bf16x8*)&bh[wn * 64 + nf * 16 + r16][g * 8];
      fbl[nf] = *(const bf16x8*)&bl[wn * 64 + nf * 16 + r16][g * 8];
    }
#pragma unroll
    for (int mf = 0; mf < 4; ++mf)
#pragma unroll
      for (int nf = 0; nf < 4; ++nf) {
        acc[mf][nf] = __builtin_amdgcn_mfma_f32_16x16x32_bf16(fah[mf], fbh[nf], acc[mf][nf], 0, 0, 0);
        acc[mf][nf] = __builtin_amdgcn_mfma_f32_16x16x32_bf16(fah[mf], fbl[nf], acc[mf][nf], 0, 0, 0);
        acc[mf][nf] = __builtin_amdgcn_mfma_f32_16x16x32_bf16(fal[mf], fbh[nf], acc[mf][nf], 0, 0, 0);
      }
    __syncthreads();
  }

  // epilogue: C/D layout col=lane&15, row=(lane>>4)*4+reg  [m89-verified]
#pragma unroll
  for (int mf = 0; mf < 4; ++mf) {
#pragma unroll
    for (int reg = 0; reg < 4; ++reg) {
      int row = row0 + wm * 64 + mf * 16 + g * 4 + reg;
      if (row < n) {
#pragma unroll
        for (int nf = 0; nf < 4; ++nf) {
          out[(size_t)row * 128 + wn * 64 + nf * 16 + r16] = acc[mf][nf][reg];
        }
      }
    }
  }
}

// ---------------- f32 tiled GEMM (NC=64 cases) ----------------
template <int K, int NC>
__global__ __launch_bounds__(256) void gemm_kernel(const float* __restrict__ A,
                                                   const float* __restrict__ B,
                                                   const float* __restrict__ bias, int do_relu,
                                                   float* __restrict__ out, int n) {
  constexpr int CG = NC / 4;
  constexpr int RG = 256 / CG;
  constexpr int ROWS = RG * 4;
  constexpr int KT = K / 32;

  __shared__ __align__(16) float xs[ROWS][36];
  __shared__ __align__(16) float ws[32][NC];

  const int tid = threadIdx.x;
  const int tc = tid % CG;
  const int tr = tid / CG;
  const int row0 = blockIdx.x * ROWS;

  float4 acc0 = make_float4(0, 0, 0, 0);
  float4 acc1 = acc0, acc2 = acc0, acc3 = acc0;

  for (int kt = 0; kt < KT; ++kt) {
    const int k0 = kt * 32;
    for (int idx = tid; idx < ROWS * 8; idx += 256) {
      int r = idx >> 3, c4 = (idx & 7) * 4;
      float4 v = make_float4(0, 0, 0, 0);
      if (row0 + r < n) v = *(const float4*)&A[(size_t)(row0 + r) * K + k0 + c4];
      *(float4*)&xs[r][c4] = v;
    }
    for (int idx = tid; idx < 8 * NC; idx += 256) {
      int kr = idx / CG, c4 = (idx % CG) * 4;
      *(float4*)&ws[kr][c4] = *(const float4*)&B[(size_t)(k0 + kr) * NC + c4];
    }
    __syncthreads();
#pragma unroll
    for (int kk = 0; kk < 32; kk += 4) {
      float4 a0 = *(const float4*)&xs[tr * 4 + 0][kk];
      float4 a1 = *(const float4*)&xs[tr * 4 + 1][kk];
      float4 a2 = *(const float4*)&xs[tr * 4 + 2][kk];
      float4 a3 = *(const float4*)&xs[tr * 4 + 3][kk];
      const float* f0 = (const float*)&a0;
      const float* f1 = (const float*)&a1;
      const float* f2 = (const float*)&a2;
      const float* f3 = (const float*)&a3;
#pragma unroll
      for (int q = 0; q < 4; ++q) {
        float4 b = *(const float4*)&ws[kk + q][tc * 4];
        fma4(acc0, f0[q], b);
        fma4(acc1, f1[q], b);
        fma4(acc2, f2[q], b);
        fma4(acc3, f3[q], b);
      }
    }
    __syncthreads();
  }

  float4 bv = make_float4(0, 0, 0, 0);
  if (bias) bv = *(const float4*)&bias[tc * 4];
  float4 accs[4] = {acc0, acc1, acc2, acc3};
#pragma unroll
  for (int i = 0; i < 4; ++i) {
    int row = row0 + tr * 4 + i;
    if (row < n) {
      float4 v = accs[i];
      v.x += bv.x; v.y += bv.y; v.z += bv.z; v.w += bv.w;
      if (do_relu) {
        v.x = fmaxf(v.x, 0.f); v.y = fmaxf(v.y, 0.f);
        v.z = fmaxf(v.z, 0.f); v.w = fmaxf(v.w, 0.f);
      }
      *(float4*)&out[(size_t)row * NC + tc * 4] = v;
    }
  }
}

// ---------------- combine + attention scores + interleave h ----------------
__global__ __launch_bounds__(256) void comb_att2_kernel(const float* __restrict__ P0,
                                                        const float* __restrict__ a_src,
                                                        const float* __restrict__ a_dst,
                                                        float2* __restrict__ h2,
                                                        float2* __restrict__ s2,
                                                        float2* __restrict__ t2, int n) {
  int wid = (blockIdx.x * 256 + threadIdx.x) >> 6;
  int lane = threadIdx.x & 63;
  if (wid >= n) return;
  float h0 = P0[(size_t)wid * 128 + lane];
  float h1 = P0[(size_t)wid * 128 + 64 + lane];
  h2[(size_t)wid * 64 + lane] = make_float2(h0, h1);
  float v0 = h0 * a_src[lane];
  float v1 = h1 * a_src[64 + lane];
  float v2 = h0 * a_dst[lane];
  float v3 = h1 * a_dst[64 + lane];
#pragma unroll
  for (int off = 32; off > 0; off >>= 1) {
    v0 += __shfl_xor(v0, off);
    v1 += __shfl_xor(v1, off);
    v2 += __shfl_xor(v2, off);
    v3 += __shfl_xor(v3, off);
  }
  if (lane == 0) {
    s2[wid] = make_float2(v0, v1);
    t2[wid] = make_float2(v2, v3);
  }
}

__global__ __launch_bounds__(256) void att1_kernel(const float* __restrict__ h,
                                                   const float* __restrict__ a_src,
                                                   const float* __restrict__ a_dst,
                                                   float* __restrict__ s, float* __restrict__ t,
                                                   int n) {
  int wid = (blockIdx.x * 256 + threadIdx.x) >> 6;
  int lane = threadIdx.x & 63;
  if (wid >= n) return;
  float h0 = h[(size_t)wid * 64 + lane];
  float v0 = h0 * a_src[lane];
  float v1 = h0 * a_dst[lane];
#pragma unroll
  for (int off = 32; off > 0; off >>= 1) {
    v0 += __shfl_xor(v0, off);
    v1 += __shfl_xor(v1, off);
  }
  if (lane == 0) {
    s[wid] = v0;
    t[wid] = v1;
  }
}

// ---------------- two-pass softmax aggregation, H=2, gathers from interleaved h2 ----------------
__global__ __launch_bounds__(256) void agg2_kernel(const float2* __restrict__ h2,
                                                   const float2* __restrict__ s2,
                                                   const float2* __restrict__ t2,
                                                   const int* __restrict__ row_ptr,
                                                   const int* __restrict__ col_src,
                                                   const float* __restrict__ bias,
                                                   float* __restrict__ out, int n, int do_relu) {
  int wid = (blockIdx.x * 256 + threadIdx.x) >> 6;
  int lane = threadIdx.x & 63;
  if (wid >= n) return;
  const int node = wid;
  const float2 tt = t2[node];
  const float t0 = tt.x, t1 = tt.y;
  const int beg = row_ptr[node], end = row_ptr[node + 1];

  float2 sself = s2[node];
  const float e_self0 = lrelu(sself.x + t0);
  const float e_self1 = lrelu(sself.y + t1);
  float m0 = e_self0, m1 = e_self1;
  for (int i = beg + lane; i < end; i += 64) {
    float2 sv = s2[col_src[i]];
    m0 = fmaxf(m0, lrelu(sv.x + t0));
    m1 = fmaxf(m1, lrelu(sv.y + t1));
  }
#pragma unroll
  for (int off = 32; off > 0; off >>= 1) {
    m0 = fmaxf(m0, __shfl_xor(m0, off));
    m1 = fmaxf(m1, __shfl_xor(m1, off));
  }

  float p0 = __expf(e_self0 - m0);
  float p1 = __expf(e_self1 - m1);
  float d0 = p0, d1 = p1;
  float2 hself = h2[(size_t)node * 64 + lane];
  float acc0 = p0 * hself.x;
  float acc1 = p1 * hself.y;

  for (int base = beg; base < end; base += 64) {
    int i = base + lane;
    int srcn = node;
    float q0 = 0.f, q1 = 0.f;
    if (i < end) {
      srcn = col_src[i];
      float2 sv = s2[srcn];
      q0 = __expf(lrelu(sv.x + t0) - m0);
      q1 = __expf(lrelu(sv.y + t1) - m1);
    }
    const int cnt = min(64, end - base);
    const int cnt4 = (cnt + 3) & ~3;
    int i0 = __shfl(srcn, 0), i1 = __shfl(srcn, 1), i2 = __shfl(srcn, 2), i3 = __shfl(srcn, 3);
    float2 b0 = h2[(size_t)i0 * 64 + lane];
    float2 b1 = h2[(size_t)i1 * 64 + lane];
    float2 b2 = h2[(size_t)i2 * 64 + lane];
    float2 b3 = h2[(size_t)i3 * 64 + lane];
    for (int j = 0; j < cnt4; j += 4) {
      float p00 = __shfl(q0, j),     p01 = __shfl(q1, j);
      float p10 = __shfl(q0, j + 1), p11 = __shfl(q1, j + 1);
      float p20 = __shfl(q0, j + 2), p21 = __shfl(q1, j + 2);
      float p30 = __shfl(q0, j + 3), p31 = __shfl(q1, j + 3);
      float2 c0 = b0, c1 = b1, c2 = b2, c3 = b3;
      if (j + 4 < cnt4) {
        int n0 = __shfl(srcn, j + 4), n1 = __shfl(srcn, j + 5);
        int n2 = __shfl(srcn, j + 6), n3 = __shfl(srcn, j + 7);
        b0 = h2[(size_t)n0 * 64 + lane];
        b1 = h2[(size_t)n1 * 64 + lane];
        b2 = h2[(size_t)n2 * 64 + lane];
        b3 = h2[(size_t)n3 * 64 + lane];
      }
      d0 += p00 + p10 + p20 + p30;
      d1 += p01 + p11 + p21 + p31;
      acc0 = fmaf(p00, c0.x, acc0);
      acc1 = fmaf(p01, c0.y, acc1);
      acc0 = fmaf(p10, c1.x, acc0);
      acc1 = fmaf(p11, c1.y, acc1);
      acc0 = fmaf(p20, c2.x, acc0);
      acc1 = fmaf(p21, c2.y, acc1);
      acc0 = fmaf(p30, c3.x, acc0);
      acc1 = fmaf(p31, c3.y, acc1);
    }
  }

  float o0 = acc0 / (d0 + 1e-16f) + bias[lane];
  float o1 = acc1 / (d1 + 1e-16f) + bias[64 + lane];
  if (do_relu) {
    o0 = fmaxf(o0, 0.f);
    o1 = fmaxf(o1, 0.f);
  }
  out[(size_t)node * 128 + lane] = o0;
  out[(size_t)node * 128 + 64 + lane] = o1;
}

// ---------------- two-pass softmax aggregation, H=1, C=64 ----------------
__global__ __launch_bounds__(256) void agg1_kernel(const float* __restrict__ h,
                                                   const float* __restrict__ s,
                                                   const float* __restrict__ t,
                                                   const int* __restrict__ row_ptr,
                                                   const int* __restrict__ col_src,
                                                   const float* __restrict__ bias,
                                                   float* __restrict__ out, int n) {
  int wid = (blockIdx.x * 256 + threadIdx.x) >> 6;
  int lane = threadIdx.x & 63;
  if (wid >= n) return;
  const int node = wid;
  const float t0 = t[node];
  const int beg = row_ptr[node], end = row_ptr[node + 1];

  const float e_self = lrelu(s[node] + t0);
  float m0 = e_self;
  for (int i = beg + lane; i < end; i += 64) {
    m0 = fmaxf(m0, lrelu(s[col_src[i]] + t0));
  }
#pragma unroll
  for (int off = 32; off > 0; off >>= 1) m0 = fmaxf(m0, __shfl_xor(m0, off));

  float p = __expf(e_self - m0);
  float d0 = p;
  float acc0 = p * h[(size_t)node * 64 + lane];

  for (int base = beg; base < end; base += 64) {
    int i = base + lane;
    int srcn = node;
    float q0 = 0.f;
    if (i < end) {
      srcn = col_src[i];
      q0 = __expf(lrelu(s[srcn] + t0) - m0);
    }
    const int cnt = min(64, end - base);
    const int cnt4 = (cnt + 3) & ~3;
    int i0 = __shfl(srcn, 0), i1 = __shfl(srcn, 1), i2 = __shfl(srcn, 2), i3 = __shfl(srcn, 3);
    float b0 = h[(size_t)i0 * 64 + lane];
    float b1 = h[(size_t)i1 * 64 + lane];
    float b2 = h[(size_t)i2 * 64 + lane];
    float b3 = h[(size_t)i3 * 64 + lane];
    for (int j = 0; j < cnt4; j += 4) {
      float p0 = __shfl(q0, j),     p1 = __shfl(q0, j + 1);
      float p2 = __shfl(q0, j + 2), p3 = __shfl(q0, j + 3);
      float c0 = b0, c1 = b1, c2 = b2, c3 = b3;
      if (j + 4 < cnt4) {
        int n0 = __shfl(srcn, j + 4), n1 = __shfl(srcn, j + 5);
        int n2 = __shfl(srcn, j + 6), n3 = __shfl(srcn, j + 7);
        b0 = h[(size_t)n0 * 64 + lane];
        b1 = h[(size_t)n1 * 64 + lane];
        b2 = h[(size_t)n2 * 64 + lane];
        b3 = h[(size_t)n3 * 64 + lane];
      }
      d0 += p0 + p1 + p2 + p3;
      acc0 = fmaf(p0, c0, acc0);
      acc0 = fmaf(p1, c1, acc0);
      acc0 = fmaf(p2, c2, acc0);
      acc0 = fmaf(p3, c3, acc0);
    }
  }
  out[(size_t)node * 64 + lane] = acc0 / (d0 + 1e-16f) + bias[lane];
}

extern "C" void kernel_launch(void* const* d_in, const int* in_sizes, int n_in,
                              void* d_out, int out_size, void* d_ws, size_t ws_size,
                              hipStream_t stream) {
  const float* x       = (const float*)d_in[0];
  const int*   ei      = (const int*)d_in[1];
  const float* W0      = (const float*)d_in[2];
  const float* a_src0  = (const float*)d_in[3];
  const float* a_dst0  = (const float*)d_in[4];
  const float* b0      = (const float*)d_in[5];
  const float* W1      = (const float*)d_in[6];
  const float* a_src1  = (const float*)d_in[7];
  const float* a_dst1  = (const float*)d_in[8];
  const float* b1      = (const float*)d_in[9];
  const float* W2      = (const float*)d_in[10];
  const float* a_src2  = (const float*)d_in[11];
  const float* a_dst2  = (const float*)d_in[12];
  const float* b2      = (const float*)d_in[13];
  const float* Wv      = (const float*)d_in[14];
  const float* bv      = (const float*)d_in[15];
  const float* Wt      = (const float*)d_in[16];
  const float* bt      = (const float*)d_in[17];

  const int n = NN, E = NE;

  char* w = (char*)d_ws;
  int* counts  = (int*)w;   w += (size_t)n * 4;
  int* row_ptr = (int*)w;   w += (size_t)(n + 4) * 4;
  int* cursor  = (int*)w;   w += (size_t)n * 4;
  int* col_src = (int*)w;   w += (size_t)E * 4;
  float2* s2   = (float2*)w; w += (size_t)n * 8;
  float2* t2   = (float2*)w; w += (size_t)n * 8;
  float* Abuf  = (float*)w;  w += (size_t)n * 128 * 4;   // 25.6 MB
  float2* h2   = (float2*)w; w += (size_t)n * 64 * 8;    // 25.6 MB
  float* P0    = (float*)w;  w += (size_t)n * 128 * 4;   // 25.6 MB
  ushort_t* wt0h = (ushort_t*)w; w += (size_t)128 * 512 * 2;  // 128 KB
  ushort_t* wt0l = (ushort_t*)w; w += (size_t)128 * 512 * 2;
  ushort_t* wt1h = (ushort_t*)w; w += (size_t)128 * 128 * 2;  // 32 KB
  ushort_t* wt1l = (ushort_t*)w; w += (size_t)128 * 128 * 2;

  float* hbuf = (float*)h2;          // layer-2 h [N,64] reuses h2 region
  float* s1   = (float*)s2;
  float* t1   = (float*)t2;

  float* out_h = (float*)d_out;
  float* out_v = out_h + (size_t)n * 64;
  float* out_t = out_v + (size_t)n * 64;

  // ---- CSR build + W prep ----
  hipMemsetAsync(counts, 0, (size_t)n * 4, stream);
  hipMemsetAsync(cursor, 0, (size_t)n * 4, stream);
  count_kernel<<<(E + 255) / 256, 256, 0, stream>>>(ei, counts, E);
  prep_wt_kernel<<<(128 * 32 + 255) / 256, 256, 0, stream>>>(W0, 512, 128, wt0h, wt0l);
  prep_wt_kernel<<<(128 * 8 + 255) / 256, 256, 0, stream>>>(W1, 128, 128, wt1h, wt1l);
  scan_kernel<<<1, 1024, 0, stream>>>(counts, row_ptr, n);
  fill_kernel<<<(E + 255) / 256, 256, 0, stream>>>(ei, row_ptr, cursor, col_src, E);

  const int wgrid = (n + 3) / 4;
  const int g128 = (n + 127) / 128;

  // ---- layer 0: x[N,512] @ W0 (MFMA bf16-split) ----
  gemm_mfma_kernel<512><<<g128, 256, 0, stream>>>(x, wt0h, wt0l, P0, n);
  comb_att2_kernel<<<wgrid, 256, 0, stream>>>(P0, a_src0, a_dst0, h2, s2, t2, n);
  agg2_kernel<<<wgrid, 256, 0, stream>>>(h2, s2, t2, row_ptr, col_src, b0, Abuf, n, 1);

  // ---- layer 1: Abuf[N,128] @ W1 (MFMA bf16-split) ----
  gemm_mfma_kernel<128><<<g128, 256, 0, stream>>>(Abuf, wt1h, wt1l, P0, n);
  comb_att2_kernel<<<wgrid, 256, 0, stream>>>(P0, a_src1, a_dst1, h2, s2, t2, n);
  agg2_kernel<<<wgrid, 256, 0, stream>>>(h2, s2, t2, row_ptr, col_src, b1, Abuf, n, 1);

  // ---- layer 2: Abuf[N,128] @ W2 -> hbuf[N,64] ----
  gemm_kernel<128, 64><<<(n + 63) / 64, 256, 0, stream>>>(Abuf, W2, nullptr, 0, hbuf, n);
  att1_kernel<<<wgrid, 256, 0, stream>>>(hbuf, a_src2, a_dst2, s1, t1, n);
  agg1_kernel<<<wgrid, 256, 0, stream>>>(hbuf, s1, t1, row_ptr, col_src, b2, out_h, n);

  // ---- MLP heads ----
  gemm_kernel<64, 64><<<(n + 63) / 64, 256, 0, stream>>>(out_h, Wv, bv, 1, out_v, n);
  gemm_kernel<64, 64><<<(n + 63) / 64, 256, 0, stream>>>(out_h, Wt, bt, 1, out_t, n);
}

// Round 5
// 420.804 us; speedup vs baseline: 1.5852x; 1.1782x over previous
//
#include <hip/hip_runtime.h>
#include <hip/hip_bf16.h>
#include <math.h>

#define NN 50000
#define NE 800000

typedef unsigned short ushort_t;
typedef unsigned int uint_t;
typedef __attribute__((ext_vector_type(8))) short bf16x8;
typedef __attribute__((ext_vector_type(4))) float f32x4;

__device__ __forceinline__ float lrelu(float x) { return x >= 0.f ? x : 0.2f * x; }

__device__ __forceinline__ ushort_t f2bf_rn(float f) {
  uint_t u = __builtin_bit_cast(uint_t, f);
  uint_t r = u + 0x7FFFu + ((u >> 16) & 1u);
  return (ushort_t)(r >> 16);
}
__device__ __forceinline__ float bf2f(ushort_t h) {
  uint_t u = ((uint_t)h) << 16;
  return __builtin_bit_cast(float, u);
}

// ---------------- CSR build (dst-indexed) ----------------
__global__ void count_kernel(const int* __restrict__ ei, int* __restrict__ counts, int E) {
  int e = blockIdx.x * blockDim.x + threadIdx.x;
  if (e < E) atomicAdd(&counts[ei[E + e]], 1);
}

// hierarchical scan: (1) per-block sums, (2) scan of block sums, (3) per-block exclusive scan
__global__ __launch_bounds__(256) void scan_blocksum_kernel(const int* __restrict__ counts,
                                                            int* __restrict__ bsums, int n) {
  __shared__ int red[4];
  int i = blockIdx.x * 256 + threadIdx.x;
  int v = (i < n) ? counts[i] : 0;
#pragma unroll
  for (int off = 32; off > 0; off >>= 1) v += __shfl_down(v, off);
  if ((threadIdx.x & 63) == 0) red[threadIdx.x >> 6] = v;
  __syncthreads();
  if (threadIdx.x == 0) bsums[blockIdx.x] = red[0] + red[1] + red[2] + red[3];
}

__global__ __launch_bounds__(256) void scan_offsets_kernel(int* __restrict__ bsums, int nb) {
  __shared__ int sm[256];
  int tid = threadIdx.x;
  int v = (tid < nb) ? bsums[tid] : 0;
  sm[tid] = v;
  __syncthreads();
  for (int off = 1; off < 256; off <<= 1) {
    int u = (tid >= off) ? sm[tid - off] : 0;
    __syncthreads();
    sm[tid] += u;
    __syncthreads();
  }
  if (tid < nb) bsums[tid] = sm[tid] - v;  // exclusive
}

__global__ __launch_bounds__(256) void scan_final_kernel(const int* __restrict__ counts,
                                                         const int* __restrict__ boffs,
                                                         int* __restrict__ row_ptr, int n, int E) {
  __shared__ int sm[256];
  int tid = threadIdx.x;
  int i = blockIdx.x * 256 + tid;
  int v = (i < n) ? counts[i] : 0;
  int orig = v;
  sm[tid] = v;
  __syncthreads();
  for (int off = 1; off < 256; off <<= 1) {
    int u = (tid >= off) ? sm[tid - off] : 0;
    __syncthreads();
    sm[tid] += u;
    __syncthreads();
  }
  if (i < n) row_ptr[i] = boffs[blockIdx.x] + sm[tid] - orig;
  if (i == n) row_ptr[n] = E;
}

__global__ void fill_kernel(const int* __restrict__ ei, const int* __restrict__ row_ptr,
                            int* __restrict__ cursor, int* __restrict__ col_src, int E) {
  int e = blockIdx.x * blockDim.x + threadIdx.x;
  if (e < E) {
    int d = ei[E + e];
    int pos = row_ptr[d] + atomicAdd(&cursor[d], 1);
    col_src[pos] = ei[e];
  }
}

// ---------------- W prep: transpose + bf16 hi/lo split. W[K][C] -> wt[C][K] ----------------
__global__ void prep_wt_kernel(const float* __restrict__ W, int Kdim, int C,
                               ushort_t* __restrict__ wth, ushort_t* __restrict__ wtl) {
  int t = blockIdx.x * blockDim.x + threadIdx.x;
  int nk = Kdim >> 4;
  if (t >= C * nk) return;
  int c = t / nk, kc = (t % nk) << 4;
  uint_t hw[8], lw[8];
#pragma unroll
  for (int i = 0; i < 8; ++i) {
    float f0 = W[(size_t)(kc + 2 * i) * C + c];
    float f1 = W[(size_t)(kc + 2 * i + 1) * C + c];
    ushort_t h0 = f2bf_rn(f0), h1 = f2bf_rn(f1);
    ushort_t l0 = f2bf_rn(f0 - bf2f(h0)), l1 = f2bf_rn(f1 - bf2f(h1));
    hw[i] = (uint_t)h0 | ((uint_t)h1 << 16);
    lw[i] = (uint_t)l0 | ((uint_t)l1 << 16);
  }
  uint_t* ph = (uint_t*)&wth[(size_t)c * Kdim + kc];
  uint_t* pl = (uint_t*)&wtl[(size_t)c * Kdim + kc];
  *(uint4*)ph = make_uint4(hw[0], hw[1], hw[2], hw[3]);
  *(uint4*)(ph + 4) = make_uint4(hw[4], hw[5], hw[6], hw[7]);
  *(uint4*)pl = make_uint4(lw[0], lw[1], lw[2], lw[3]);
  *(uint4*)(pl + 4) = make_uint4(lw[4], lw[5], lw[6], lw[7]);
}

// ---------------- MFMA GEMM: out[n,128] = A[n,K]f32 @ W[K,128], bf16 3-term split ----------------
template <int K>
__global__ __launch_bounds__(256, 2) void gemm_mfma_kernel(const float* __restrict__ A,
                                                           const ushort_t* __restrict__ wth,
                                                           const ushort_t* __restrict__ wtl,
                                                           float* __restrict__ out, int n) {
  __shared__ __align__(16) ushort_t ah[128][40];
  __shared__ __align__(16) ushort_t al[128][40];
  __shared__ __align__(16) ushort_t bh[128][40];
  __shared__ __align__(16) ushort_t bl[128][40];

  const int t = threadIdx.x;
  const int row0 = blockIdx.x * 128;
  const int srow = t >> 1;
  const int skq = (t & 1) * 16;

  const int lane = t & 63;
  const int wid = t >> 6;
  const int wm = wid >> 1, wn = wid & 1;
  const int r16 = lane & 15, g = lane >> 4;

  f32x4 acc[4][4];
#pragma unroll
  for (int i = 0; i < 4; ++i)
#pragma unroll
    for (int j = 0; j < 4; ++j) acc[i][j] = (f32x4)(0.f);

  for (int kt = 0; kt < K / 32; ++kt) {
    const int k0 = kt * 32;
    {
      uint_t hw[8], lw[8];
      if (row0 + srow < n) {
        const float* ap = &A[(size_t)(row0 + srow) * K + k0 + skq];
#pragma unroll
        for (int j = 0; j < 4; ++j) {
          float4 v = *(const float4*)(ap + j * 4);
          ushort_t h0 = f2bf_rn(v.x), h1 = f2bf_rn(v.y), h2 = f2bf_rn(v.z), h3 = f2bf_rn(v.w);
          ushort_t l0 = f2bf_rn(v.x - bf2f(h0)), l1 = f2bf_rn(v.y - bf2f(h1));
          ushort_t l2 = f2bf_rn(v.z - bf2f(h2)), l3 = f2bf_rn(v.w - bf2f(h3));
          hw[j * 2] = (uint_t)h0 | ((uint_t)h1 << 16);
          hw[j * 2 + 1] = (uint_t)h2 | ((uint_t)h3 << 16);
          lw[j * 2] = (uint_t)l0 | ((uint_t)l1 << 16);
          lw[j * 2 + 1] = (uint_t)l2 | ((uint_t)l3 << 16);
        }
      } else {
#pragma unroll
        for (int j = 0; j < 8; ++j) { hw[j] = 0; lw[j] = 0; }
      }
      *(uint4*)&ah[srow][skq] = make_uint4(hw[0], hw[1], hw[2], hw[3]);
      *(uint4*)&ah[srow][skq + 8] = make_uint4(hw[4], hw[5], hw[6], hw[7]);
      *(uint4*)&al[srow][skq] = make_uint4(lw[0], lw[1], lw[2], lw[3]);
      *(uint4*)&al[srow][skq + 8] = make_uint4(lw[4], lw[5], lw[6], lw[7]);
    }
    {
      const ushort_t* ph = &wth[(size_t)srow * K + k0 + skq];
      const ushort_t* pl = &wtl[(size_t)srow * K + k0 + skq];
      uint4 vh0 = *(const uint4*)ph;
      uint4 vh1 = *(const uint4*)(ph + 8);
      uint4 vl0 = *(const uint4*)pl;
      uint4 vl1 = *(const uint4*)(pl + 8);
      *(uint4*)&bh[srow][skq] = vh0;
      *(uint4*)&bh[srow][skq + 8] = vh1;
      *(uint4*)&bl[srow][skq] = vl0;
      *(uint4*)&bl[srow][skq + 8] = vl1;
    }
    __syncthreads();

    bf16x8 fah[4], fal[4], fbh[4], fbl[4];
#pragma unroll
    for (int mf = 0; mf < 4; ++mf) {
      fah[mf] = *(const bf16x8*)&ah[wm * 64 + mf * 16 + r16][g * 8];
      fal[mf] = *(const bf16x8*)&al[wm * 64 + mf * 16 + r16][g * 8];
    }
#pragma unroll
    for (int nf = 0; nf < 4; ++nf) {
      fbh[nf] = *(const bf16x8*)&bh[wn * 64 + nf * 16 + r16][g * 8];
      fbl[nf] = *(const bf16x8*)&bl[wn * 64 + nf * 16 + r16][g * 8];
    }
#pragma unroll
    for (int mf = 0; mf < 4; ++mf)
#pragma unroll
      for (int nf = 0; nf < 4; ++nf) {
        acc[mf][nf] = __builtin_amdgcn_mfma_f32_16x16x32_bf16(fah[mf], fbh[nf], acc[mf][nf], 0, 0, 0);
        acc[mf][nf] = __builtin_amdgcn_mfma_f32_16x16x32_bf16(fah[mf], fbl[nf], acc[mf][nf], 0, 0, 0);
        acc[mf][nf] = __builtin_amdgcn_mfma_f32_16x16x32_bf16(fal[mf], fbh[nf], acc[mf][nf], 0, 0, 0);
      }
    __syncthreads();
  }

#pragma unroll
  for (int mf = 0; mf < 4; ++mf) {
#pragma unroll
    for (int reg = 0; reg < 4; ++reg) {
      int row = row0 + wm * 64 + mf * 16 + g * 4 + reg;
      if (row < n) {
#pragma unroll
        for (int nf = 0; nf < 4; ++nf) {
          out[(size_t)row * 128 + wn * 64 + nf * 16 + r16] = acc[mf][nf][reg];
        }
      }
    }
  }
}

// ---------------- MFMA GEMM: out[n,64] = A[n,K]f32 @ W[K,64], bf16 3-term split ----------------
template <int K>
__global__ __launch_bounds__(256, 2) void gemm_mfma64_kernel(const float* __restrict__ A,
                                                             const ushort_t* __restrict__ wth,
                                                             const ushort_t* __restrict__ wtl,
                                                             const float* __restrict__ bias,
                                                             int do_relu,
                                                             float* __restrict__ out, int n) {
  __shared__ __align__(16) ushort_t ah[128][40];
  __shared__ __align__(16) ushort_t al[128][40];
  __shared__ __align__(16) ushort_t bh[64][40];
  __shared__ __align__(16) ushort_t bl[64][40];

  const int t = threadIdx.x;
  const int row0 = blockIdx.x * 128;
  const int srow = t >> 1;
  const int skq = (t & 1) * 16;
  const int bcol = t >> 2;
  const int bkq = (t & 3) * 8;

  const int lane = t & 63;
  const int wid = t >> 6;   // wave owns rows wid*32..+31
  const int r16 = lane & 15, g = lane >> 4;

  f32x4 acc[2][4];
#pragma unroll
  for (int i = 0; i < 2; ++i)
#pragma unroll
    for (int j = 0; j < 4; ++j) acc[i][j] = (f32x4)(0.f);

  for (int kt = 0; kt < K / 32; ++kt) {
    const int k0 = kt * 32;
    {
      uint_t hw[8], lw[8];
      if (row0 + srow < n) {
        const float* ap = &A[(size_t)(row0 + srow) * K + k0 + skq];
#pragma unroll
        for (int j = 0; j < 4; ++j) {
          float4 v = *(const float4*)(ap + j * 4);
          ushort_t h0 = f2bf_rn(v.x), h1 = f2bf_rn(v.y), h2 = f2bf_rn(v.z), h3 = f2bf_rn(v.w);
          ushort_t l0 = f2bf_rn(v.x - bf2f(h0)), l1 = f2bf_rn(v.y - bf2f(h1));
          ushort_t l2 = f2bf_rn(v.z - bf2f(h2)), l3 = f2bf_rn(v.w - bf2f(h3));
          hw[j * 2] = (uint_t)h0 | ((uint_t)h1 << 16);
          hw[j * 2 + 1] = (uint_t)h2 | ((uint_t)h3 << 16);
          lw[j * 2] = (uint_t)l0 | ((uint_t)l1 << 16);
          lw[j * 2 + 1] = (uint_t)l2 | ((uint_t)l3 << 16);
        }
      } else {
#pragma unroll
        for (int j = 0; j < 8; ++j) { hw[j] = 0; lw[j] = 0; }
      }
      *(uint4*)&ah[srow][skq] = make_uint4(hw[0], hw[1], hw[2], hw[3]);
      *(uint4*)&ah[srow][skq + 8] = make_uint4(hw[4], hw[5], hw[6], hw[7]);
      *(uint4*)&al[srow][skq] = make_uint4(lw[0], lw[1], lw[2], lw[3]);
      *(uint4*)&al[srow][skq + 8] = make_uint4(lw[4], lw[5], lw[6], lw[7]);
    }
    {
      uint4 vh = *(const uint4*)&wth[(size_t)bcol * K + k0 + bkq];
      uint4 vl = *(const uint4*)&wtl[(size_t)bcol * K + k0 + bkq];
      *(uint4*)&bh[bcol][bkq] = vh;
      *(uint4*)&bl[bcol][bkq] = vl;
    }
    __syncthreads();

    bf16x8 fah[2], fal[2], fbh[4], fbl[4];
#pragma unroll
    for (int mf = 0; mf < 2; ++mf) {
      fah[mf] = *(const bf16x8*)&ah[wid * 32 + mf * 16 + r16][g * 8];
      fal[mf] = *(const bf16x8*)&al[wid * 32 + mf * 16 + r16][g * 8];
    }
#pragma unroll
    for (int nf = 0; nf < 4; ++nf) {
      fbh[nf] = *(const bf16x8*)&bh[nf * 16 + r16][g * 8];
      fbl[nf] = *(const bf16x8*)&bl[nf * 16 + r16][g * 8];
    }
#pragma unroll
    for (int mf = 0; mf < 2; ++mf)
#pragma unroll
      for (int nf = 0; nf < 4; ++nf) {
        acc[mf][nf] = __builtin_amdgcn_mfma_f32_16x16x32_bf16(fah[mf], fbh[nf], acc[mf][nf], 0, 0, 0);
        acc[mf][nf] = __builtin_amdgcn_mfma_f32_16x16x32_bf16(fah[mf], fbl[nf], acc[mf][nf], 0, 0, 0);
        acc[mf][nf] = __builtin_amdgcn_mfma_f32_16x16x32_bf16(fal[mf], fbh[nf], acc[mf][nf], 0, 0, 0);
      }
    __syncthreads();
  }

#pragma unroll
  for (int mf = 0; mf < 2; ++mf) {
#pragma unroll
    for (int reg = 0; reg < 4; ++reg) {
      int row = row0 + wid * 32 + mf * 16 + g * 4 + reg;
      if (row < n) {
#pragma unroll
        for (int nf = 0; nf < 4; ++nf) {
          int col = nf * 16 + r16;
          float v = acc[mf][nf][reg];
          if (bias) v += bias[col];
          if (do_relu) v = fmaxf(v, 0.f);
          out[(size_t)row * 64 + col] = v;
        }
      }
    }
  }
}

// ---------------- combine + attention scores + interleave h ----------------
__global__ __launch_bounds__(256) void comb_att2_kernel(const float* __restrict__ P0,
                                                        const float* __restrict__ a_src,
                                                        const float* __restrict__ a_dst,
                                                        float2* __restrict__ h2,
                                                        float2* __restrict__ s2,
                                                        float2* __restrict__ t2, int n) {
  int wid = (blockIdx.x * 256 + threadIdx.x) >> 6;
  int lane = threadIdx.x & 63;
  if (wid >= n) return;
  float h0 = P0[(size_t)wid * 128 + lane];
  float h1 = P0[(size_t)wid * 128 + 64 + lane];
  h2[(size_t)wid * 64 + lane] = make_float2(h0, h1);
  float v0 = h0 * a_src[lane];
  float v1 = h1 * a_src[64 + lane];
  float v2 = h0 * a_dst[lane];
  float v3 = h1 * a_dst[64 + lane];
#pragma unroll
  for (int off = 32; off > 0; off >>= 1) {
    v0 += __shfl_xor(v0, off);
    v1 += __shfl_xor(v1, off);
    v2 += __shfl_xor(v2, off);
    v3 += __shfl_xor(v3, off);
  }
  if (lane == 0) {
    s2[wid] = make_float2(v0, v1);
    t2[wid] = make_float2(v2, v3);
  }
}

__global__ __launch_bounds__(256) void att1_kernel(const float* __restrict__ h,
                                                   const float* __restrict__ a_src,
                                                   const float* __restrict__ a_dst,
                                                   float* __restrict__ s, float* __restrict__ t,
                                                   int n) {
  int wid = (blockIdx.x * 256 + threadIdx.x) >> 6;
  int lane = threadIdx.x & 63;
  if (wid >= n) return;
  float h0 = h[(size_t)wid * 64 + lane];
  float v0 = h0 * a_src[lane];
  float v1 = h0 * a_dst[lane];
#pragma unroll
  for (int off = 32; off > 0; off >>= 1) {
    v0 += __shfl_xor(v0, off);
    v1 += __shfl_xor(v1, off);
  }
  if (lane == 0) {
    s[wid] = v0;
    t[wid] = v1;
  }
}

// ---------------- two-pass softmax aggregation, H=2, gathers from interleaved h2 ----------------
__global__ __launch_bounds__(256) void agg2_kernel(const float2* __restrict__ h2,
                                                   const float2* __restrict__ s2,
                                                   const float2* __restrict__ t2,
                                                   const int* __restrict__ row_ptr,
                                                   const int* __restrict__ col_src,
                                                   const float* __restrict__ bias,
                                                   float* __restrict__ out, int n, int do_relu) {
  int wid = (blockIdx.x * 256 + threadIdx.x) >> 6;
  int lane = threadIdx.x & 63;
  if (wid >= n) return;
  const int node = wid;
  const float2 tt = t2[node];
  const float t0 = tt.x, t1 = tt.y;
  const int beg = row_ptr[node], end = row_ptr[node + 1];

  float2 sself = s2[node];
  const float e_self0 = lrelu(sself.x + t0);
  const float e_self1 = lrelu(sself.y + t1);
  float m0 = e_self0, m1 = e_self1;
  for (int i = beg + lane; i < end; i += 64) {
    float2 sv = s2[col_src[i]];
    m0 = fmaxf(m0, lrelu(sv.x + t0));
    m1 = fmaxf(m1, lrelu(sv.y + t1));
  }
#pragma unroll
  for (int off = 32; off > 0; off >>= 1) {
    m0 = fmaxf(m0, __shfl_xor(m0, off));
    m1 = fmaxf(m1, __shfl_xor(m1, off));
  }

  float p0 = __expf(e_self0 - m0);
  float p1 = __expf(e_self1 - m1);
  float d0 = p0, d1 = p1;
  float2 hself = h2[(size_t)node * 64 + lane];
  float acc0 = p0 * hself.x;
  float acc1 = p1 * hself.y;

  for (int base = beg; base < end; base += 64) {
    int i = base + lane;
    int srcn = node;
    float q0 = 0.f, q1 = 0.f;
    if (i < end) {
      srcn = col_src[i];
      float2 sv = s2[srcn];
      q0 = __expf(lrelu(sv.x + t0) - m0);
      q1 = __expf(lrelu(sv.y + t1) - m1);
    }
    const int cnt = min(64, end - base);
    const int cnt4 = (cnt + 3) & ~3;
    int i0 = __shfl(srcn, 0), i1 = __shfl(srcn, 1), i2 = __shfl(srcn, 2), i3 = __shfl(srcn, 3);
    float2 b0 = h2[(size_t)i0 * 64 + lane];
    float2 b1 = h2[(size_t)i1 * 64 + lane];
    float2 b2 = h2[(size_t)i2 * 64 + lane];
    float2 b3 = h2[(size_t)i3 * 64 + lane];
    for (int j = 0; j < cnt4; j += 4) {
      float p00 = __shfl(q0, j),     p01 = __shfl(q1, j);
      float p10 = __shfl(q0, j + 1), p11 = __shfl(q1, j + 1);
      float p20 = __shfl(q0, j + 2), p21 = __shfl(q1, j + 2);
      float p30 = __shfl(q0, j + 3), p31 = __shfl(q1, j + 3);
      float2 c0 = b0, c1 = b1, c2 = b2, c3 = b3;
      if (j + 4 < cnt4) {
        int n0 = __shfl(srcn, j + 4), n1 = __shfl(srcn, j + 5);
        int n2 = __shfl(srcn, j + 6), n3 = __shfl(srcn, j + 7);
        b0 = h2[(size_t)n0 * 64 + lane];
        b1 = h2[(size_t)n1 * 64 + lane];
        b2 = h2[(size_t)n2 * 64 + lane];
        b3 = h2[(size_t)n3 * 64 + lane];
      }
      d0 += p00 + p10 + p20 + p30;
      d1 += p01 + p11 + p21 + p31;
      acc0 = fmaf(p00, c0.x, acc0);
      acc1 = fmaf(p01, c0.y, acc1);
      acc0 = fmaf(p10, c1.x, acc0);
      acc1 = fmaf(p11, c1.y, acc1);
      acc0 = fmaf(p20, c2.x, acc0);
      acc1 = fmaf(p21, c2.y, acc1);
      acc0 = fmaf(p30, c3.x, acc0);
      acc1 = fmaf(p31, c3.y, acc1);
    }
  }

  float o0 = acc0 / (d0 + 1e-16f) + bias[lane];
  float o1 = acc1 / (d1 + 1e-16f) + bias[64 + lane];
  if (do_relu) {
    o0 = fmaxf(o0, 0.f);
    o1 = fmaxf(o1, 0.f);
  }
  out[(size_t)node * 128 + lane] = o0;
  out[(size_t)node * 128 + 64 + lane] = o1;
}

// ---------------- two-pass softmax aggregation, H=1, C=64 ----------------
__global__ __launch_bounds__(256) void agg1_kernel(const float* __restrict__ h,
                                                   const float* __restrict__ s,
                                                   const float* __restrict__ t,
                                                   const int* __restrict__ row_ptr,
                                                   const int* __restrict__ col_src,
                                                   const float* __restrict__ bias,
                                                   float* __restrict__ out, int n) {
  int wid = (blockIdx.x * 256 + threadIdx.x) >> 6;
  int lane = threadIdx.x & 63;
  if (wid >= n) return;
  const int node = wid;
  const float t0 = t[node];
  const int beg = row_ptr[node], end = row_ptr[node + 1];

  const float e_self = lrelu(s[node] + t0);
  float m0 = e_self;
  for (int i = beg + lane; i < end; i += 64) {
    m0 = fmaxf(m0, lrelu(s[col_src[i]] + t0));
  }
#pragma unroll
  for (int off = 32; off > 0; off >>= 1) m0 = fmaxf(m0, __shfl_xor(m0, off));

  float p = __expf(e_self - m0);
  float d0 = p;
  float acc0 = p * h[(size_t)node * 64 + lane];

  for (int base = beg; base < end; base += 64) {
    int i = base + lane;
    int srcn = node;
    float q0 = 0.f;
    if (i < end) {
      srcn = col_src[i];
      q0 = __expf(lrelu(s[srcn] + t0) - m0);
    }
    const int cnt = min(64, end - base);
    const int cnt4 = (cnt + 3) & ~3;
    int i0 = __shfl(srcn, 0), i1 = __shfl(srcn, 1), i2 = __shfl(srcn, 2), i3 = __shfl(srcn, 3);
    float b0 = h[(size_t)i0 * 64 + lane];
    float b1 = h[(size_t)i1 * 64 + lane];
    float b2 = h[(size_t)i2 * 64 + lane];
    float b3 = h[(size_t)i3 * 64 + lane];
    for (int j = 0; j < cnt4; j += 4) {
      float p0 = __shfl(q0, j),     p1 = __shfl(q0, j + 1);
      float p2 = __shfl(q0, j + 2), p3 = __shfl(q0, j + 3);
      float c0 = b0, c1 = b1, c2 = b2, c3 = b3;
      if (j + 4 < cnt4) {
        int n0 = __shfl(srcn, j + 4), n1 = __shfl(srcn, j + 5);
        int n2 = __shfl(srcn, j + 6), n3 = __shfl(srcn, j + 7);
        b0 = h[(size_t)n0 * 64 + lane];
        b1 = h[(size_t)n1 * 64 + lane];
        b2 = h[(size_t)n2 * 64 + lane];
        b3 = h[(size_t)n3 * 64 + lane];
      }
      d0 += p0 + p1 + p2 + p3;
      acc0 = fmaf(p0, c0, acc0);
      acc0 = fmaf(p1, c1, acc0);
      acc0 = fmaf(p2, c2, acc0);
      acc0 = fmaf(p3, c3, acc0);
    }
  }
  out[(size_t)node * 64 + lane] = acc0 / (d0 + 1e-16f) + bias[lane];
}

extern "C" void kernel_launch(void* const* d_in, const int* in_sizes, int n_in,
                              void* d_out, int out_size, void* d_ws, size_t ws_size,
                              hipStream_t stream) {
  const float* x       = (const float*)d_in[0];
  const int*   ei      = (const int*)d_in[1];
  const float* W0      = (const float*)d_in[2];
  const float* a_src0  = (const float*)d_in[3];
  const float* a_dst0  = (const float*)d_in[4];
  const float* b0      = (const float*)d_in[5];
  const float* W1      = (const float*)d_in[6];
  const float* a_src1  = (const float*)d_in[7];
  const float* a_dst1  = (const float*)d_in[8];
  const float* b1      = (const float*)d_in[9];
  const float* W2      = (const float*)d_in[10];
  const float* a_src2  = (const float*)d_in[11];
  const float* a_dst2  = (const float*)d_in[12];
  const float* b2      = (const float*)d_in[13];
  const float* Wv      = (const float*)d_in[14];
  const float* bv      = (const float*)d_in[15];
  const float* Wt      = (const float*)d_in[16];
  const float* bt      = (const float*)d_in[17];

  const int n = NN, E = NE;
  const int NB = (n + 255) / 256;         // 196 scan blocks
  const int NBF = (n + 1 + 255) / 256;    // covers i==n

  char* w = (char*)d_ws;
  int* counts  = (int*)w;   w += (size_t)n * 4;
  int* row_ptr = (int*)w;   w += (size_t)(n + 4) * 4;
  int* cursor  = (int*)w;   w += (size_t)n * 4;
  int* bsums   = (int*)w;   w += (size_t)256 * 4;
  int* col_src = (int*)w;   w += (size_t)E * 4;
  float2* s2   = (float2*)w; w += (size_t)n * 8;
  float2* t2   = (float2*)w; w += (size_t)n * 8;
  float* Abuf  = (float*)w;  w += (size_t)n * 128 * 4;   // 25.6 MB
  float2* h2   = (float2*)w; w += (size_t)n * 64 * 8;    // 25.6 MB
  float* P0    = (float*)w;  w += (size_t)n * 128 * 4;   // 25.6 MB
  ushort_t* wt0h = (ushort_t*)w; w += (size_t)128 * 512 * 2;
  ushort_t* wt0l = (ushort_t*)w; w += (size_t)128 * 512 * 2;
  ushort_t* wt1h = (ushort_t*)w; w += (size_t)128 * 128 * 2;
  ushort_t* wt1l = (ushort_t*)w; w += (size_t)128 * 128 * 2;
  ushort_t* wt2h = (ushort_t*)w; w += (size_t)64 * 128 * 2;
  ushort_t* wt2l = (ushort_t*)w; w += (size_t)64 * 128 * 2;
  ushort_t* wvh  = (ushort_t*)w; w += (size_t)64 * 64 * 2;
  ushort_t* wvl  = (ushort_t*)w; w += (size_t)64 * 64 * 2;
  ushort_t* wtth = (ushort_t*)w; w += (size_t)64 * 64 * 2;
  ushort_t* wttl = (ushort_t*)w; w += (size_t)64 * 64 * 2;

  float* hbuf = (float*)h2;          // layer-2 h [N,64] reuses h2 region
  float* s1   = (float*)s2;
  float* t1   = (float*)t2;

  float* out_h = (float*)d_out;
  float* out_v = out_h + (size_t)n * 64;
  float* out_t = out_v + (size_t)n * 64;

  // ---- CSR build + W prep ----
  hipMemsetAsync(counts, 0, (size_t)n * 4, stream);
  hipMemsetAsync(cursor, 0, (size_t)n * 4, stream);
  count_kernel<<<(E + 255) / 256, 256, 0, stream>>>(ei, counts, E);
  prep_wt_kernel<<<(128 * 32 + 255) / 256, 256, 0, stream>>>(W0, 512, 128, wt0h, wt0l);
  prep_wt_kernel<<<(128 * 8 + 255) / 256, 256, 0, stream>>>(W1, 128, 128, wt1h, wt1l);
  prep_wt_kernel<<<(64 * 8 + 255) / 256, 256, 0, stream>>>(W2, 128, 64, wt2h, wt2l);
  prep_wt_kernel<<<(64 * 4 + 255) / 256, 256, 0, stream>>>(Wv, 64, 64, wvh, wvl);
  prep_wt_kernel<<<(64 * 4 + 255) / 256, 256, 0, stream>>>(Wt, 64, 64, wtth, wttl);
  scan_blocksum_kernel<<<NB, 256, 0, stream>>>(counts, bsums, n);
  scan_offsets_kernel<<<1, 256, 0, stream>>>(bsums, NB);
  scan_final_kernel<<<NBF, 256, 0, stream>>>(counts, bsums, row_ptr, n, E);
  fill_kernel<<<(E + 255) / 256, 256, 0, stream>>>(ei, row_ptr, cursor, col_src, E);

  const int wgrid = (n + 3) / 4;
  const int g128 = (n + 127) / 128;

  // ---- layer 0: x[N,512] @ W0 (MFMA) ----
  gemm_mfma_kernel<512><<<g128, 256, 0, stream>>>(x, wt0h, wt0l, P0, n);
  comb_att2_kernel<<<wgrid, 256, 0, stream>>>(P0, a_src0, a_dst0, h2, s2, t2, n);
  agg2_kernel<<<wgrid, 256, 0, stream>>>(h2, s2, t2, row_ptr, col_src, b0, Abuf, n, 1);

  // ---- layer 1: Abuf[N,128] @ W1 (MFMA) ----
  gemm_mfma_kernel<128><<<g128, 256, 0, stream>>>(Abuf, wt1h, wt1l, P0, n);
  comb_att2_kernel<<<wgrid, 256, 0, stream>>>(P0, a_src1, a_dst1, h2, s2, t2, n);
  agg2_kernel<<<wgrid, 256, 0, stream>>>(h2, s2, t2, row_ptr, col_src, b1, Abuf, n, 1);

  // ---- layer 2: Abuf[N,128] @ W2 -> hbuf[N,64] (MFMA) ----
  gemm_mfma64_kernel<128><<<g128, 256, 0, stream>>>(Abuf, wt2h, wt2l, nullptr, 0, hbuf, n);
  att1_kernel<<<wgrid, 256, 0, stream>>>(hbuf, a_src2, a_dst2, s1, t1, n);
  agg1_kernel<<<wgrid, 256, 0, stream>>>(hbuf, s1, t1, row_ptr, col_src, b2, out_h, n);

  // ---- MLP heads (MFMA) ----
  gemm_mfma64_kernel<64><<<g128, 256, 0, stream>>>(out_h, wvh, wvl, bv, 1, out_v, n);
  gemm_mfma64_kernel<64><<<g128, 256, 0, stream>>>(out_h, wtth, wttl, bt, 1, out_t, n);
}

// Round 6
// 358.006 us; speedup vs baseline: 1.8633x; 1.1754x over previous
//
#include <hip/hip_runtime.h>
#include <hip/hip_bf16.h>
#include <hip/hip_fp16.h>
#include <math.h>

#define NN 50000
#define NE 800000

typedef unsigned short ushort_t;
typedef unsigned int uint_t;
typedef __attribute__((ext_vector_type(8))) short bf16x8;
typedef __attribute__((ext_vector_type(4))) float f32x4;

__device__ __forceinline__ float lrelu(float x) { return x >= 0.f ? x : 0.2f * x; }

__device__ __forceinline__ ushort_t f2bf_rn(float f) {
  uint_t u = __builtin_bit_cast(uint_t, f);
  uint_t r = u + 0x7FFFu + ((u >> 16) & 1u);
  return (ushort_t)(r >> 16);
}
__device__ __forceinline__ float bf2f(ushort_t h) {
  uint_t u = ((uint_t)h) << 16;
  return __builtin_bit_cast(float, u);
}

// ---------------- CSR build (dst-indexed) ----------------
__global__ void count_kernel(const int* __restrict__ ei, int* __restrict__ counts, int E) {
  int e = blockIdx.x * blockDim.x + threadIdx.x;
  if (e < E) atomicAdd(&counts[ei[E + e]], 1);
}

__global__ __launch_bounds__(256) void scan_blocksum_kernel(const int* __restrict__ counts,
                                                            int* __restrict__ bsums, int n) {
  __shared__ int red[4];
  int i = blockIdx.x * 256 + threadIdx.x;
  int v = (i < n) ? counts[i] : 0;
#pragma unroll
  for (int off = 32; off > 0; off >>= 1) v += __shfl_down(v, off);
  if ((threadIdx.x & 63) == 0) red[threadIdx.x >> 6] = v;
  __syncthreads();
  if (threadIdx.x == 0) bsums[blockIdx.x] = red[0] + red[1] + red[2] + red[3];
}

__global__ __launch_bounds__(256) void scan_offsets_kernel(int* __restrict__ bsums, int nb) {
  __shared__ int sm[256];
  int tid = threadIdx.x;
  int v = (tid < nb) ? bsums[tid] : 0;
  sm[tid] = v;
  __syncthreads();
  for (int off = 1; off < 256; off <<= 1) {
    int u = (tid >= off) ? sm[tid - off] : 0;
    __syncthreads();
    sm[tid] += u;
    __syncthreads();
  }
  if (tid < nb) bsums[tid] = sm[tid] - v;  // exclusive
}

__global__ __launch_bounds__(256) void scan_final_kernel(const int* __restrict__ counts,
                                                         const int* __restrict__ boffs,
                                                         int* __restrict__ row_ptr, int n, int E) {
  __shared__ int sm[256];
  int tid = threadIdx.x;
  int i = blockIdx.x * 256 + tid;
  int v = (i < n) ? counts[i] : 0;
  int orig = v;
  sm[tid] = v;
  __syncthreads();
  for (int off = 1; off < 256; off <<= 1) {
    int u = (tid >= off) ? sm[tid - off] : 0;
    __syncthreads();
    sm[tid] += u;
    __syncthreads();
  }
  if (i < n) row_ptr[i] = boffs[blockIdx.x] + sm[tid] - orig;
  if (i == n) row_ptr[n] = E;
}

__global__ void fill_kernel(const int* __restrict__ ei, const int* __restrict__ row_ptr,
                            int* __restrict__ cursor, int* __restrict__ col_src, int E) {
  int e = blockIdx.x * blockDim.x + threadIdx.x;
  if (e < E) {
    int d = ei[E + e];
    int pos = row_ptr[d] + atomicAdd(&cursor[d], 1);
    col_src[pos] = ei[e];
  }
}

// ---------------- W prep: transpose + bf16 hi/lo split. W[K][C] -> wt[C][K] ----------------
__global__ void prep_wt_kernel(const float* __restrict__ W, int Kdim, int C,
                               ushort_t* __restrict__ wth, ushort_t* __restrict__ wtl) {
  int t = blockIdx.x * blockDim.x + threadIdx.x;
  int nk = Kdim >> 4;
  if (t >= C * nk) return;
  int c = t / nk, kc = (t % nk) << 4;
  uint_t hw[8], lw[8];
#pragma unroll
  for (int i = 0; i < 8; ++i) {
    float f0 = W[(size_t)(kc + 2 * i) * C + c];
    float f1 = W[(size_t)(kc + 2 * i + 1) * C + c];
    ushort_t h0 = f2bf_rn(f0), h1 = f2bf_rn(f1);
    ushort_t l0 = f2bf_rn(f0 - bf2f(h0)), l1 = f2bf_rn(f1 - bf2f(h1));
    hw[i] = (uint_t)h0 | ((uint_t)h1 << 16);
    lw[i] = (uint_t)l0 | ((uint_t)l1 << 16);
  }
  uint_t* ph = (uint_t*)&wth[(size_t)c * Kdim + kc];
  uint_t* pl = (uint_t*)&wtl[(size_t)c * Kdim + kc];
  *(uint4*)ph = make_uint4(hw[0], hw[1], hw[2], hw[3]);
  *(uint4*)(ph + 4) = make_uint4(hw[4], hw[5], hw[6], hw[7]);
  *(uint4*)pl = make_uint4(lw[0], lw[1], lw[2], lw[3]);
  *(uint4*)(pl + 4) = make_uint4(lw[4], lw[5], lw[6], lw[7]);
}

// ---------------- MFMA GEMM: out[n,128] = A[n,K]f32 @ W[K,128], bf16 3-term split ----------------
template <int K>
__global__ __launch_bounds__(256, 2) void gemm_mfma_kernel(const float* __restrict__ A,
                                                           const ushort_t* __restrict__ wth,
                                                           const ushort_t* __restrict__ wtl,
                                                           float* __restrict__ out, int n) {
  __shared__ __align__(16) ushort_t ah[128][40];
  __shared__ __align__(16) ushort_t al[128][40];
  __shared__ __align__(16) ushort_t bh[128][40];
  __shared__ __align__(16) ushort_t bl[128][40];

  const int t = threadIdx.x;
  const int row0 = blockIdx.x * 128;
  const int srow = t >> 1;
  const int skq = (t & 1) * 16;

  const int lane = t & 63;
  const int wid = t >> 6;
  const int wm = wid >> 1, wn = wid & 1;
  const int r16 = lane & 15, g = lane >> 4;

  f32x4 acc[4][4];
#pragma unroll
  for (int i = 0; i < 4; ++i)
#pragma unroll
    for (int j = 0; j < 4; ++j) acc[i][j] = (f32x4)(0.f);

  for (int kt = 0; kt < K / 32; ++kt) {
    const int k0 = kt * 32;
    {
      uint_t hw[8], lw[8];
      if (row0 + srow < n) {
        const float* ap = &A[(size_t)(row0 + srow) * K + k0 + skq];
#pragma unroll
        for (int j = 0; j < 4; ++j) {
          float4 v = *(const float4*)(ap + j * 4);
          ushort_t h0 = f2bf_rn(v.x), h1 = f2bf_rn(v.y), h2 = f2bf_rn(v.z), h3 = f2bf_rn(v.w);
          ushort_t l0 = f2bf_rn(v.x - bf2f(h0)), l1 = f2bf_rn(v.y - bf2f(h1));
          ushort_t l2 = f2bf_rn(v.z - bf2f(h2)), l3 = f2bf_rn(v.w - bf2f(h3));
          hw[j * 2] = (uint_t)h0 | ((uint_t)h1 << 16);
          hw[j * 2 + 1] = (uint_t)h2 | ((uint_t)h3 << 16);
          lw[j * 2] = (uint_t)l0 | ((uint_t)l1 << 16);
          lw[j * 2 + 1] = (uint_t)l2 | ((uint_t)l3 << 16);
        }
      } else {
#pragma unroll
        for (int j = 0; j < 8; ++j) { hw[j] = 0; lw[j] = 0; }
      }
      *(uint4*)&ah[srow][skq] = make_uint4(hw[0], hw[1], hw[2], hw[3]);
      *(uint4*)&ah[srow][skq + 8] = make_uint4(hw[4], hw[5], hw[6], hw[7]);
      *(uint4*)&al[srow][skq] = make_uint4(lw[0], lw[1], lw[2], lw[3]);
      *(uint4*)&al[srow][skq + 8] = make_uint4(lw[4], lw[5], lw[6], lw[7]);
    }
    {
      const ushort_t* ph = &wth[(size_t)srow * K + k0 + skq];
      const ushort_t* pl = &wtl[(size_t)srow * K + k0 + skq];
      uint4 vh0 = *(const uint4*)ph;
      uint4 vh1 = *(const uint4*)(ph + 8);
      uint4 vl0 = *(const uint4*)pl;
      uint4 vl1 = *(const uint4*)(pl + 8);
      *(uint4*)&bh[srow][skq] = vh0;
      *(uint4*)&bh[srow][skq + 8] = vh1;
      *(uint4*)&bl[srow][skq] = vl0;
      *(uint4*)&bl[srow][skq + 8] = vl1;
    }
    __syncthreads();

    bf16x8 fah[4], fal[4], fbh[4], fbl[4];
#pragma unroll
    for (int mf = 0; mf < 4; ++mf) {
      fah[mf] = *(const bf16x8*)&ah[wm * 64 + mf * 16 + r16][g * 8];
      fal[mf] = *(const bf16x8*)&al[wm * 64 + mf * 16 + r16][g * 8];
    }
#pragma unroll
    for (int nf = 0; nf < 4; ++nf) {
      fbh[nf] = *(const bf16x8*)&bh[wn * 64 + nf * 16 + r16][g * 8];
      fbl[nf] = *(const bf16x8*)&bl[wn * 64 + nf * 16 + r16][g * 8];
    }
#pragma unroll
    for (int mf = 0; mf < 4; ++mf)
#pragma unroll
      for (int nf = 0; nf < 4; ++nf) {
        acc[mf][nf] = __builtin_amdgcn_mfma_f32_16x16x32_bf16(fah[mf], fbh[nf], acc[mf][nf], 0, 0, 0);
        acc[mf][nf] = __builtin_amdgcn_mfma_f32_16x16x32_bf16(fah[mf], fbl[nf], acc[mf][nf], 0, 0, 0);
        acc[mf][nf] = __builtin_amdgcn_mfma_f32_16x16x32_bf16(fal[mf], fbh[nf], acc[mf][nf], 0, 0, 0);
      }
    __syncthreads();
  }

#pragma unroll
  for (int mf = 0; mf < 4; ++mf) {
#pragma unroll
    for (int reg = 0; reg < 4; ++reg) {
      int row = row0 + wm * 64 + mf * 16 + g * 4 + reg;
      if (row < n) {
#pragma unroll
        for (int nf = 0; nf < 4; ++nf) {
          out[(size_t)row * 128 + wn * 64 + nf * 16 + r16] = acc[mf][nf][reg];
        }
      }
    }
  }
}

// ---------------- MFMA GEMM: out[n,64] = A[n,K]f32 @ W[K,64], bf16 3-term split ----------------
template <int K>
__global__ __launch_bounds__(256, 2) void gemm_mfma64_kernel(const float* __restrict__ A,
                                                             const ushort_t* __restrict__ wth,
                                                             const ushort_t* __restrict__ wtl,
                                                             const float* __restrict__ bias,
                                                             int do_relu,
                                                             float* __restrict__ out, int n) {
  __shared__ __align__(16) ushort_t ah[128][40];
  __shared__ __align__(16) ushort_t al[128][40];
  __shared__ __align__(16) ushort_t bh[64][40];
  __shared__ __align__(16) ushort_t bl[64][40];

  const int t = threadIdx.x;
  const int row0 = blockIdx.x * 128;
  const int srow = t >> 1;
  const int skq = (t & 1) * 16;
  const int bcol = t >> 2;
  const int bkq = (t & 3) * 8;

  const int lane = t & 63;
  const int wid = t >> 6;
  const int r16 = lane & 15, g = lane >> 4;

  f32x4 acc[2][4];
#pragma unroll
  for (int i = 0; i < 2; ++i)
#pragma unroll
    for (int j = 0; j < 4; ++j) acc[i][j] = (f32x4)(0.f);

  for (int kt = 0; kt < K / 32; ++kt) {
    const int k0 = kt * 32;
    {
      uint_t hw[8], lw[8];
      if (row0 + srow < n) {
        const float* ap = &A[(size_t)(row0 + srow) * K + k0 + skq];
#pragma unroll
        for (int j = 0; j < 4; ++j) {
          float4 v = *(const float4*)(ap + j * 4);
          ushort_t h0 = f2bf_rn(v.x), h1 = f2bf_rn(v.y), h2 = f2bf_rn(v.z), h3 = f2bf_rn(v.w);
          ushort_t l0 = f2bf_rn(v.x - bf2f(h0)), l1 = f2bf_rn(v.y - bf2f(h1));
          ushort_t l2 = f2bf_rn(v.z - bf2f(h2)), l3 = f2bf_rn(v.w - bf2f(h3));
          hw[j * 2] = (uint_t)h0 | ((uint_t)h1 << 16);
          hw[j * 2 + 1] = (uint_t)h2 | ((uint_t)h3 << 16);
          lw[j * 2] = (uint_t)l0 | ((uint_t)l1 << 16);
          lw[j * 2 + 1] = (uint_t)l2 | ((uint_t)l3 << 16);
        }
      } else {
#pragma unroll
        for (int j = 0; j < 8; ++j) { hw[j] = 0; lw[j] = 0; }
      }
      *(uint4*)&ah[srow][skq] = make_uint4(hw[0], hw[1], hw[2], hw[3]);
      *(uint4*)&ah[srow][skq + 8] = make_uint4(hw[4], hw[5], hw[6], hw[7]);
      *(uint4*)&al[srow][skq] = make_uint4(lw[0], lw[1], lw[2], lw[3]);
      *(uint4*)&al[srow][skq + 8] = make_uint4(lw[4], lw[5], lw[6], lw[7]);
    }
    {
      uint4 vh = *(const uint4*)&wth[(size_t)bcol * K + k0 + bkq];
      uint4 vl = *(const uint4*)&wtl[(size_t)bcol * K + k0 + bkq];
      *(uint4*)&bh[bcol][bkq] = vh;
      *(uint4*)&bl[bcol][bkq] = vl;
    }
    __syncthreads();

    bf16x8 fah[2], fal[2], fbh[4], fbl[4];
#pragma unroll
    for (int mf = 0; mf < 2; ++mf) {
      fah[mf] = *(const bf16x8*)&ah[wid * 32 + mf * 16 + r16][g * 8];
      fal[mf] = *(const bf16x8*)&al[wid * 32 + mf * 16 + r16][g * 8];
    }
#pragma unroll
    for (int nf = 0; nf < 4; ++nf) {
      fbh[nf] = *(const bf16x8*)&bh[nf * 16 + r16][g * 8];
      fbl[nf] = *(const bf16x8*)&bl[nf * 16 + r16][g * 8];
    }
#pragma unroll
    for (int mf = 0; mf < 2; ++mf)
#pragma unroll
      for (int nf = 0; nf < 4; ++nf) {
        acc[mf][nf] = __builtin_amdgcn_mfma_f32_16x16x32_bf16(fah[mf], fbh[nf], acc[mf][nf], 0, 0, 0);
        acc[mf][nf] = __builtin_amdgcn_mfma_f32_16x16x32_bf16(fah[mf], fbl[nf], acc[mf][nf], 0, 0, 0);
        acc[mf][nf] = __builtin_amdgcn_mfma_f32_16x16x32_bf16(fal[mf], fbh[nf], acc[mf][nf], 0, 0, 0);
      }
    __syncthreads();
  }

#pragma unroll
  for (int mf = 0; mf < 2; ++mf) {
#pragma unroll
    for (int reg = 0; reg < 4; ++reg) {
      int row = row0 + wid * 32 + mf * 16 + g * 4 + reg;
      if (row < n) {
#pragma unroll
        for (int nf = 0; nf < 4; ++nf) {
          int col = nf * 16 + r16;
          float v = acc[mf][nf][reg];
          if (bias) v += bias[col];
          if (do_relu) v = fmaxf(v, 0.f);
          out[(size_t)row * 64 + col] = v;
        }
      }
    }
  }
}

// ---------------- combine + attention scores + interleaved f16 h ----------------
__global__ __launch_bounds__(256) void comb_att2_kernel(const float* __restrict__ P0,
                                                        const float* __restrict__ a_src,
                                                        const float* __restrict__ a_dst,
                                                        __half2* __restrict__ h2h,
                                                        float2* __restrict__ s2,
                                                        float2* __restrict__ t2, int n) {
  int wid = (blockIdx.x * 256 + threadIdx.x) >> 6;
  int lane = threadIdx.x & 63;
  if (wid >= n) return;
  float h0 = P0[(size_t)wid * 128 + lane];
  float h1 = P0[(size_t)wid * 128 + 64 + lane];
  h2h[(size_t)wid * 64 + lane] = __floats2half2_rn(h0, h1);
  float v0 = h0 * a_src[lane];
  float v1 = h1 * a_src[64 + lane];
  float v2 = h0 * a_dst[lane];
  float v3 = h1 * a_dst[64 + lane];
#pragma unroll
  for (int off = 32; off > 0; off >>= 1) {
    v0 += __shfl_xor(v0, off);
    v1 += __shfl_xor(v1, off);
    v2 += __shfl_xor(v2, off);
    v3 += __shfl_xor(v3, off);
  }
  if (lane == 0) {
    s2[wid] = make_float2(v0, v1);
    t2[wid] = make_float2(v2, v3);
  }
}

// att1: scores for H=1 layer + f16 copy of h
__global__ __launch_bounds__(256) void att1_kernel(const float* __restrict__ h,
                                                   const float* __restrict__ a_src,
                                                   const float* __restrict__ a_dst,
                                                   float* __restrict__ s, float* __restrict__ t,
                                                   __half* __restrict__ h16, int n) {
  int wid = (blockIdx.x * 256 + threadIdx.x) >> 6;
  int lane = threadIdx.x & 63;
  if (wid >= n) return;
  float h0 = h[(size_t)wid * 64 + lane];
  h16[(size_t)wid * 64 + lane] = __float2half(h0);
  float v0 = h0 * a_src[lane];
  float v1 = h0 * a_dst[lane];
#pragma unroll
  for (int off = 32; off > 0; off >>= 1) {
    v0 += __shfl_xor(v0, off);
    v1 += __shfl_xor(v1, off);
  }
  if (lane == 0) {
    s[wid] = v0;
    t[wid] = v1;
  }
}

// ---------------- two-pass softmax aggregation, H=2, f16 gathers ----------------
__global__ __launch_bounds__(256) void agg2_kernel(const __half2* __restrict__ h2h,
                                                   const float2* __restrict__ s2,
                                                   const float2* __restrict__ t2,
                                                   const int* __restrict__ row_ptr,
                                                   const int* __restrict__ col_src,
                                                   const float* __restrict__ bias,
                                                   float* __restrict__ out, int n, int do_relu) {
  int wid = (blockIdx.x * 256 + threadIdx.x) >> 6;
  int lane = threadIdx.x & 63;
  if (wid >= n) return;
  const int node = wid;
  const float2 tt = t2[node];
  const float t0 = tt.x, t1 = tt.y;
  const int beg = row_ptr[node], end = row_ptr[node + 1];

  float2 sself = s2[node];
  const float e_self0 = lrelu(sself.x + t0);
  const float e_self1 = lrelu(sself.y + t1);

  // lane's own first-chunk edge (kept in regs; reused in pass B for deg<=64)
  const int i_own = beg + lane;
  int src_own = node;
  float e0_own = -1e30f, e1_own = -1e30f;
  if (i_own < end) {
    src_own = col_src[i_own];
    float2 sv = s2[src_own];
    e0_own = lrelu(sv.x + t0);
    e1_own = lrelu(sv.y + t1);
  }
  float m0 = fmaxf(e_self0, e0_own), m1 = fmaxf(e_self1, e1_own);
  for (int i = beg + 64 + lane; i < end; i += 64) {
    float2 sv = s2[col_src[i]];
    m0 = fmaxf(m0, lrelu(sv.x + t0));
    m1 = fmaxf(m1, lrelu(sv.y + t1));
  }
#pragma unroll
  for (int off = 32; off > 0; off >>= 1) {
    m0 = fmaxf(m0, __shfl_xor(m0, off));
    m1 = fmaxf(m1, __shfl_xor(m1, off));
  }

  float p0 = __expf(e_self0 - m0);
  float p1 = __expf(e_self1 - m1);
  float d0 = p0, d1 = p1;
  float2 hself = __half22float2(h2h[(size_t)node * 64 + lane]);
  float acc0 = p0 * hself.x;
  float acc1 = p1 * hself.y;

  for (int base = beg; base < end; base += 64) {
    int srcn;
    float q0, q1;
    if (base == beg) {
      srcn = src_own;
      q0 = (i_own < end) ? __expf(e0_own - m0) : 0.f;
      q1 = (i_own < end) ? __expf(e1_own - m1) : 0.f;
    } else {
      int i = base + lane;
      srcn = node;
      q0 = 0.f; q1 = 0.f;
      if (i < end) {
        srcn = col_src[i];
        float2 sv = s2[srcn];
        q0 = __expf(lrelu(sv.x + t0) - m0);
        q1 = __expf(lrelu(sv.y + t1) - m1);
      }
    }
    const int cnt = min(64, end - base);
    const int cnt4 = (cnt + 3) & ~3;
    int i0 = __shfl(srcn, 0), i1 = __shfl(srcn, 1), i2 = __shfl(srcn, 2), i3 = __shfl(srcn, 3);
    __half2 b0 = h2h[(size_t)i0 * 64 + lane];
    __half2 b1 = h2h[(size_t)i1 * 64 + lane];
    __half2 b2 = h2h[(size_t)i2 * 64 + lane];
    __half2 b3 = h2h[(size_t)i3 * 64 + lane];
    for (int j = 0; j < cnt4; j += 4) {
      float p00 = __shfl(q0, j),     p01 = __shfl(q1, j);
      float p10 = __shfl(q0, j + 1), p11 = __shfl(q1, j + 1);
      float p20 = __shfl(q0, j + 2), p21 = __shfl(q1, j + 2);
      float p30 = __shfl(q0, j + 3), p31 = __shfl(q1, j + 3);
      __half2 c0 = b0, c1 = b1, c2 = b2, c3 = b3;
      if (j + 4 < cnt4) {
        int n0 = __shfl(srcn, j + 4), n1 = __shfl(srcn, j + 5);
        int n2 = __shfl(srcn, j + 6), n3 = __shfl(srcn, j + 7);
        b0 = h2h[(size_t)n0 * 64 + lane];
        b1 = h2h[(size_t)n1 * 64 + lane];
        b2 = h2h[(size_t)n2 * 64 + lane];
        b3 = h2h[(size_t)n3 * 64 + lane];
      }
      float2 f0 = __half22float2(c0), f1 = __half22float2(c1);
      float2 f2 = __half22float2(c2), f3 = __half22float2(c3);
      d0 += p00 + p10 + p20 + p30;
      d1 += p01 + p11 + p21 + p31;
      acc0 = fmaf(p00, f0.x, acc0);
      acc1 = fmaf(p01, f0.y, acc1);
      acc0 = fmaf(p10, f1.x, acc0);
      acc1 = fmaf(p11, f1.y, acc1);
      acc0 = fmaf(p20, f2.x, acc0);
      acc1 = fmaf(p21, f2.y, acc1);
      acc0 = fmaf(p30, f3.x, acc0);
      acc1 = fmaf(p31, f3.y, acc1);
    }
  }

  float o0 = acc0 / (d0 + 1e-16f) + bias[lane];
  float o1 = acc1 / (d1 + 1e-16f) + bias[64 + lane];
  if (do_relu) {
    o0 = fmaxf(o0, 0.f);
    o1 = fmaxf(o1, 0.f);
  }
  out[(size_t)node * 128 + lane] = o0;
  out[(size_t)node * 128 + 64 + lane] = o1;
}

// ---------------- two-pass softmax aggregation, H=1, f16 gathers ----------------
__global__ __launch_bounds__(256) void agg1_kernel(const __half* __restrict__ h16,
                                                   const float* __restrict__ s,
                                                   const float* __restrict__ t,
                                                   const int* __restrict__ row_ptr,
                                                   const int* __restrict__ col_src,
                                                   const float* __restrict__ bias,
                                                   float* __restrict__ out, int n) {
  int wid = (blockIdx.x * 256 + threadIdx.x) >> 6;
  int lane = threadIdx.x & 63;
  if (wid >= n) return;
  const int node = wid;
  const float t0 = t[node];
  const int beg = row_ptr[node], end = row_ptr[node + 1];

  const float e_self = lrelu(s[node] + t0);
  const int i_own = beg + lane;
  int src_own = node;
  float e_own = -1e30f;
  if (i_own < end) {
    src_own = col_src[i_own];
    e_own = lrelu(s[src_own] + t0);
  }
  float m0 = fmaxf(e_self, e_own);
  for (int i = beg + 64 + lane; i < end; i += 64) {
    m0 = fmaxf(m0, lrelu(s[col_src[i]] + t0));
  }
#pragma unroll
  for (int off = 32; off > 0; off >>= 1) m0 = fmaxf(m0, __shfl_xor(m0, off));

  float p = __expf(e_self - m0);
  float d0 = p;
  float acc0 = p * __half2float(h16[(size_t)node * 64 + lane]);

  for (int base = beg; base < end; base += 64) {
    int srcn;
    float q0;
    if (base == beg) {
      srcn = src_own;
      q0 = (i_own < end) ? __expf(e_own - m0) : 0.f;
    } else {
      int i = base + lane;
      srcn = node;
      q0 = 0.f;
      if (i < end) {
        srcn = col_src[i];
        q0 = __expf(lrelu(s[srcn] + t0) - m0);
      }
    }
    const int cnt = min(64, end - base);
    const int cnt4 = (cnt + 3) & ~3;
    int i0 = __shfl(srcn, 0), i1 = __shfl(srcn, 1), i2 = __shfl(srcn, 2), i3 = __shfl(srcn, 3);
    __half b0 = h16[(size_t)i0 * 64 + lane];
    __half b1 = h16[(size_t)i1 * 64 + lane];
    __half b2 = h16[(size_t)i2 * 64 + lane];
    __half b3 = h16[(size_t)i3 * 64 + lane];
    for (int j = 0; j < cnt4; j += 4) {
      float p0 = __shfl(q0, j),     p1 = __shfl(q0, j + 1);
      float p2 = __shfl(q0, j + 2), p3 = __shfl(q0, j + 3);
      float c0 = __half2float(b0), c1 = __half2float(b1);
      float c2 = __half2float(b2), c3 = __half2float(b3);
      if (j + 4 < cnt4) {
        int n0 = __shfl(srcn, j + 4), n1 = __shfl(srcn, j + 5);
        int n2 = __shfl(srcn, j + 6), n3 = __shfl(srcn, j + 7);
        b0 = h16[(size_t)n0 * 64 + lane];
        b1 = h16[(size_t)n1 * 64 + lane];
        b2 = h16[(size_t)n2 * 64 + lane];
        b3 = h16[(size_t)n3 * 64 + lane];
      }
      d0 += p0 + p1 + p2 + p3;
      acc0 = fmaf(p0, c0, acc0);
      acc0 = fmaf(p1, c1, acc0);
      acc0 = fmaf(p2, c2, acc0);
      acc0 = fmaf(p3, c3, acc0);
    }
  }
  out[(size_t)node * 64 + lane] = acc0 / (d0 + 1e-16f) + bias[lane];
}

extern "C" void kernel_launch(void* const* d_in, const int* in_sizes, int n_in,
                              void* d_out, int out_size, void* d_ws, size_t ws_size,
                              hipStream_t stream) {
  const float* x       = (const float*)d_in[0];
  const int*   ei      = (const int*)d_in[1];
  const float* W0      = (const float*)d_in[2];
  const float* a_src0  = (const float*)d_in[3];
  const float* a_dst0  = (const float*)d_in[4];
  const float* b0      = (const float*)d_in[5];
  const float* W1      = (const float*)d_in[6];
  const float* a_src1  = (const float*)d_in[7];
  const float* a_dst1  = (const float*)d_in[8];
  const float* b1      = (const float*)d_in[9];
  const float* W2      = (const float*)d_in[10];
  const float* a_src2  = (const float*)d_in[11];
  const float* a_dst2  = (const float*)d_in[12];
  const float* b2      = (const float*)d_in[13];
  const float* Wv      = (const float*)d_in[14];
  const float* bv      = (const float*)d_in[15];
  const float* Wt      = (const float*)d_in[16];
  const float* bt      = (const float*)d_in[17];

  const int n = NN, E = NE;
  const int NB = (n + 255) / 256;
  const int NBF = (n + 1 + 255) / 256;

  char* w = (char*)d_ws;
  int* counts  = (int*)w;   w += (size_t)n * 4;
  int* row_ptr = (int*)w;   w += (size_t)(n + 4) * 4;
  int* cursor  = (int*)w;   w += (size_t)n * 4;
  int* bsums   = (int*)w;   w += (size_t)256 * 4;
  int* col_src = (int*)w;   w += (size_t)E * 4;
  float2* s2   = (float2*)w; w += (size_t)n * 8;
  float2* t2   = (float2*)w; w += (size_t)n * 8;
  float* Abuf  = (float*)w;  w += (size_t)n * 128 * 4;   // 25.6 MB
  float* P0    = (float*)w;  w += (size_t)n * 128 * 4;   // 25.6 MB
  __half2* h2h = (__half2*)w; w += (size_t)n * 64 * 4;   // 12.8 MB
  float* hbuf  = (float*)w;  w += (size_t)n * 64 * 4;    // 12.8 MB (layer-2 h f32)
  __half* h16  = (__half*)w; w += (size_t)n * 64 * 2;    // 6.4 MB
  ushort_t* wt0h = (ushort_t*)w; w += (size_t)128 * 512 * 2;
  ushort_t* wt0l = (ushort_t*)w; w += (size_t)128 * 512 * 2;
  ushort_t* wt1h = (ushort_t*)w; w += (size_t)128 * 128 * 2;
  ushort_t* wt1l = (ushort_t*)w; w += (size_t)128 * 128 * 2;
  ushort_t* wt2h = (ushort_t*)w; w += (size_t)64 * 128 * 2;
  ushort_t* wt2l = (ushort_t*)w; w += (size_t)64 * 128 * 2;
  ushort_t* wvh  = (ushort_t*)w; w += (size_t)64 * 64 * 2;
  ushort_t* wvl  = (ushort_t*)w; w += (size_t)64 * 64 * 2;
  ushort_t* wtth = (ushort_t*)w; w += (size_t)64 * 64 * 2;
  ushort_t* wttl = (ushort_t*)w; w += (size_t)64 * 64 * 2;

  float* s1 = (float*)s2;
  float* t1 = (float*)t2;

  float* out_h = (float*)d_out;
  float* out_v = out_h + (size_t)n * 64;
  float* out_t = out_v + (size_t)n * 64;

  // ---- CSR build + W prep ----
  hipMemsetAsync(counts, 0, (size_t)n * 4, stream);
  hipMemsetAsync(cursor, 0, (size_t)n * 4, stream);
  count_kernel<<<(E + 255) / 256, 256, 0, stream>>>(ei, counts, E);
  prep_wt_kernel<<<(128 * 32 + 255) / 256, 256, 0, stream>>>(W0, 512, 128, wt0h, wt0l);
  prep_wt_kernel<<<(128 * 8 + 255) / 256, 256, 0, stream>>>(W1, 128, 128, wt1h, wt1l);
  prep_wt_kernel<<<(64 * 8 + 255) / 256, 256, 0, stream>>>(W2, 128, 64, wt2h, wt2l);
  prep_wt_kernel<<<(64 * 4 + 255) / 256, 256, 0, stream>>>(Wv, 64, 64, wvh, wvl);
  prep_wt_kernel<<<(64 * 4 + 255) / 256, 256, 0, stream>>>(Wt, 64, 64, wtth, wttl);
  scan_blocksum_kernel<<<NB, 256, 0, stream>>>(counts, bsums, n);
  scan_offsets_kernel<<<1, 256, 0, stream>>>(bsums, NB);
  scan_final_kernel<<<NBF, 256, 0, stream>>>(counts, bsums, row_ptr, n, E);
  fill_kernel<<<(E + 255) / 256, 256, 0, stream>>>(ei, row_ptr, cursor, col_src, E);

  const int wgrid = (n + 3) / 4;
  const int g128 = (n + 127) / 128;

  // ---- layer 0 ----
  gemm_mfma_kernel<512><<<g128, 256, 0, stream>>>(x, wt0h, wt0l, P0, n);
  comb_att2_kernel<<<wgrid, 256, 0, stream>>>(P0, a_src0, a_dst0, h2h, s2, t2, n);
  agg2_kernel<<<wgrid, 256, 0, stream>>>(h2h, s2, t2, row_ptr, col_src, b0, Abuf, n, 1);

  // ---- layer 1 ----
  gemm_mfma_kernel<128><<<g128, 256, 0, stream>>>(Abuf, wt1h, wt1l, P0, n);
  comb_att2_kernel<<<wgrid, 256, 0, stream>>>(P0, a_src1, a_dst1, h2h, s2, t2, n);
  agg2_kernel<<<wgrid, 256, 0, stream>>>(h2h, s2, t2, row_ptr, col_src, b1, Abuf, n, 1);

  // ---- layer 2 ----
  gemm_mfma64_kernel<128><<<g128, 256, 0, stream>>>(Abuf, wt2h, wt2l, nullptr, 0, hbuf, n);
  att1_kernel<<<wgrid, 256, 0, stream>>>(hbuf, a_src2, a_dst2, s1, t1, h16, n);
  agg1_kernel<<<wgrid, 256, 0, stream>>>(h16, s1, t1, row_ptr, col_src, b2, out_h, n);

  // ---- MLP heads ----
  gemm_mfma64_kernel<64><<<g128, 256, 0, stream>>>(out_h, wvh, wvl, bv, 1, out_v, n);
  gemm_mfma64_kernel<64><<<g128, 256, 0, stream>>>(out_h, wtth, wttl, bt, 1, out_t, n);
}

// Round 7
// 301.747 us; speedup vs baseline: 2.2107x; 1.1864x over previous
//
#include <hip/hip_runtime.h>
#include <hip/hip_bf16.h>
#include <hip/hip_fp16.h>
#include <math.h>

#define NN 50000
#define NE 800000

typedef unsigned short ushort_t;
typedef unsigned int uint_t;
typedef __attribute__((ext_vector_type(8))) short bf16x8;
typedef __attribute__((ext_vector_type(4))) float f32x4;

__device__ __forceinline__ float lrelu(float x) { return x >= 0.f ? x : 0.2f * x; }

__device__ __forceinline__ ushort_t f2bf_rn(float f) {
  uint_t u = __builtin_bit_cast(uint_t, f);
  uint_t r = u + 0x7FFFu + ((u >> 16) & 1u);
  return (ushort_t)(r >> 16);
}
__device__ __forceinline__ float bf2f(ushort_t h) {
  uint_t u = ((uint_t)h) << 16;
  return __builtin_bit_cast(float, u);
}
__device__ __forceinline__ ushort_t f2h_bits(float f) {
  __half h = __float2half(f);
  return __builtin_bit_cast(ushort_t, h);
}

// ---------------- W prep (device fn): transpose + bf16 hi/lo split. W[K][C] -> wt[C][K] ----------------
__device__ __forceinline__ void prep_dev(const float* __restrict__ W, int Kdim, int C,
                                         ushort_t* __restrict__ wth, ushort_t* __restrict__ wtl,
                                         int t) {
  int nk = Kdim >> 4;
  if (t >= C * nk) return;
  int c = t / nk, kc = (t % nk) << 4;
  uint_t hw[8], lw[8];
#pragma unroll
  for (int i = 0; i < 8; ++i) {
    float f0 = W[(size_t)(kc + 2 * i) * C + c];
    float f1 = W[(size_t)(kc + 2 * i + 1) * C + c];
    ushort_t h0 = f2bf_rn(f0), h1 = f2bf_rn(f1);
    ushort_t l0 = f2bf_rn(f0 - bf2f(h0)), l1 = f2bf_rn(f1 - bf2f(h1));
    hw[i] = (uint_t)h0 | ((uint_t)h1 << 16);
    lw[i] = (uint_t)l0 | ((uint_t)l1 << 16);
  }
  uint_t* ph = (uint_t*)&wth[(size_t)c * Kdim + kc];
  uint_t* pl = (uint_t*)&wtl[(size_t)c * Kdim + kc];
  *(uint4*)ph = make_uint4(hw[0], hw[1], hw[2], hw[3]);
  *(uint4*)(ph + 4) = make_uint4(hw[4], hw[5], hw[6], hw[7]);
  *(uint4*)pl = make_uint4(lw[0], lw[1], lw[2], lw[3]);
  *(uint4*)(pl + 4) = make_uint4(lw[4], lw[5], lw[6], lw[7]);
}

// ---------------- setup: edge count (blocks 0..3124) + all W preps (block-specialized) ----------------
#define CNT_BLOCKS 3125
__global__ __launch_bounds__(256) void setup_kernel(const int* __restrict__ ei,
                                                    int* __restrict__ counts,
                                                    const float* __restrict__ W0, ushort_t* wt0h, ushort_t* wt0l,
                                                    const float* __restrict__ W1, ushort_t* wt1h, ushort_t* wt1l,
                                                    const float* __restrict__ W2, ushort_t* wt2h, ushort_t* wt2l,
                                                    const float* __restrict__ Wv, const float* __restrict__ Wt,
                                                    ushort_t* wHh, ushort_t* wHl) {
  int b = blockIdx.x;
  if (b < CNT_BLOCKS) {
    int e = b * 256 + threadIdx.x;
    if (e < NE) atomicAdd(&counts[ei[NE + e]], 1);
    return;
  }
  b -= CNT_BLOCKS;
  if (b < 16) { prep_dev(W0, 512, 128, wt0h, wt0l, b * 256 + threadIdx.x); return; }
  b -= 16;
  if (b < 4) { prep_dev(W1, 128, 128, wt1h, wt1l, b * 256 + threadIdx.x); return; }
  b -= 4;
  if (b < 2) { prep_dev(W2, 128, 64, wt2h, wt2l, b * 256 + threadIdx.x); return; }
  b -= 2;
  if (b < 1) { prep_dev(Wv, 64, 64, wHh, wHl, b * 256 + threadIdx.x); return; }
  b -= 1;
  prep_dev(Wt, 64, 64, wHh + 64 * 64, wHl + 64 * 64, b * 256 + threadIdx.x);
}

// ---------------- hierarchical scan ----------------
__global__ __launch_bounds__(256) void scan_blocksum_kernel(const int* __restrict__ counts,
                                                            int* __restrict__ bsums, int n) {
  __shared__ int red[4];
  int i = blockIdx.x * 256 + threadIdx.x;
  int v = (i < n) ? counts[i] : 0;
#pragma unroll
  for (int off = 32; off > 0; off >>= 1) v += __shfl_down(v, off);
  if ((threadIdx.x & 63) == 0) red[threadIdx.x >> 6] = v;
  __syncthreads();
  if (threadIdx.x == 0) bsums[blockIdx.x] = red[0] + red[1] + red[2] + red[3];
}

__global__ __launch_bounds__(256) void scan_offsets_kernel(int* __restrict__ bsums, int nb) {
  __shared__ int sm[256];
  int tid = threadIdx.x;
  int v = (tid < nb) ? bsums[tid] : 0;
  sm[tid] = v;
  __syncthreads();
  for (int off = 1; off < 256; off <<= 1) {
    int u = (tid >= off) ? sm[tid - off] : 0;
    __syncthreads();
    sm[tid] += u;
    __syncthreads();
  }
  if (tid < nb) bsums[tid] = sm[tid] - v;  // exclusive
}

__global__ __launch_bounds__(256) void scan_final_kernel(const int* __restrict__ counts,
                                                         const int* __restrict__ boffs,
                                                         int* __restrict__ row_ptr,
                                                         int* __restrict__ cursor, int n, int E) {
  __shared__ int sm[256];
  int tid = threadIdx.x;
  int i = blockIdx.x * 256 + tid;
  int v = (i < n) ? counts[i] : 0;
  int orig = v;
  sm[tid] = v;
  __syncthreads();
  for (int off = 1; off < 256; off <<= 1) {
    int u = (tid >= off) ? sm[tid - off] : 0;
    __syncthreads();
    sm[tid] += u;
    __syncthreads();
  }
  if (i < n) {
    row_ptr[i] = boffs[blockIdx.x] + sm[tid] - orig;
    cursor[i] = 0;
  }
  if (i == n) row_ptr[n] = E;
}

__global__ void fill_kernel(const int* __restrict__ ei, const int* __restrict__ row_ptr,
                            int* __restrict__ cursor, int* __restrict__ col_src, int E) {
  int e = blockIdx.x * blockDim.x + threadIdx.x;
  if (e < E) {
    int d = ei[E + e];
    int pos = row_ptr[d] + atomicAdd(&cursor[d], 1);
    col_src[pos] = ei[e];
  }
}

// ---------------- MFMA GEMM + fused att2: h2h(f16) + s,t; A[n,K]f32 @ W[K,128] ----------------
template <int K>
__global__ __launch_bounds__(256, 2) void gemm_mfma_att_kernel(const float* __restrict__ A,
                                                               const ushort_t* __restrict__ wth,
                                                               const ushort_t* __restrict__ wtl,
                                                               const float* __restrict__ a_src,
                                                               const float* __restrict__ a_dst,
                                                               __half2* __restrict__ h2h,
                                                               float* __restrict__ s_arr,
                                                               float* __restrict__ t_arr, int n) {
  __shared__ __align__(16) ushort_t smem[20480];
  ushort_t (*ah)[40] = (ushort_t(*)[40])smem;
  ushort_t (*al)[40] = (ushort_t(*)[40])(smem + 5120);
  ushort_t (*bh)[40] = (ushort_t(*)[40])(smem + 10240);
  ushort_t (*bl)[40] = (ushort_t(*)[40])(smem + 15360);

  const int t = threadIdx.x;
  const int row0 = blockIdx.x * 128;
  const int srow = t >> 1;
  const int skq = (t & 1) * 16;

  const int lane = t & 63;
  const int wid = t >> 6;
  const int wm = wid >> 1, wn = wid & 1;
  const int r16 = lane & 15, g = lane >> 4;

  f32x4 acc[4][4];
#pragma unroll
  for (int i = 0; i < 4; ++i)
#pragma unroll
    for (int j = 0; j < 4; ++j) acc[i][j] = (f32x4)(0.f);

  for (int kt = 0; kt < K / 32; ++kt) {
    const int k0 = kt * 32;
    {
      uint_t hw[8], lw[8];
      if (row0 + srow < n) {
        const float* ap = &A[(size_t)(row0 + srow) * K + k0 + skq];
#pragma unroll
        for (int j = 0; j < 4; ++j) {
          float4 v = *(const float4*)(ap + j * 4);
          ushort_t h0 = f2bf_rn(v.x), h1 = f2bf_rn(v.y), h2 = f2bf_rn(v.z), h3 = f2bf_rn(v.w);
          ushort_t l0 = f2bf_rn(v.x - bf2f(h0)), l1 = f2bf_rn(v.y - bf2f(h1));
          ushort_t l2 = f2bf_rn(v.z - bf2f(h2)), l3 = f2bf_rn(v.w - bf2f(h3));
          hw[j * 2] = (uint_t)h0 | ((uint_t)h1 << 16);
          hw[j * 2 + 1] = (uint_t)h2 | ((uint_t)h3 << 16);
          lw[j * 2] = (uint_t)l0 | ((uint_t)l1 << 16);
          lw[j * 2 + 1] = (uint_t)l2 | ((uint_t)l3 << 16);
        }
      } else {
#pragma unroll
        for (int j = 0; j < 8; ++j) { hw[j] = 0; lw[j] = 0; }
      }
      *(uint4*)&ah[srow][skq] = make_uint4(hw[0], hw[1], hw[2], hw[3]);
      *(uint4*)&ah[srow][skq + 8] = make_uint4(hw[4], hw[5], hw[6], hw[7]);
      *(uint4*)&al[srow][skq] = make_uint4(lw[0], lw[1], lw[2], lw[3]);
      *(uint4*)&al[srow][skq + 8] = make_uint4(lw[4], lw[5], lw[6], lw[7]);
    }
    {
      const ushort_t* ph = &wth[(size_t)srow * K + k0 + skq];
      const ushort_t* pl = &wtl[(size_t)srow * K + k0 + skq];
      uint4 vh0 = *(const uint4*)ph;
      uint4 vh1 = *(const uint4*)(ph + 8);
      uint4 vl0 = *(const uint4*)pl;
      uint4 vl1 = *(const uint4*)(pl + 8);
      *(uint4*)&bh[srow][skq] = vh0;
      *(uint4*)&bh[srow][skq + 8] = vh1;
      *(uint4*)&bl[srow][skq] = vl0;
      *(uint4*)&bl[srow][skq + 8] = vl1;
    }
    __syncthreads();

    bf16x8 fah[4], fal[4], fbh[4], fbl[4];
#pragma unroll
    for (int mf = 0; mf < 4; ++mf) {
      fah[mf] = *(const bf16x8*)&ah[wm * 64 + mf * 16 + r16][g * 8];
      fal[mf] = *(const bf16x8*)&al[wm * 64 + mf * 16 + r16][g * 8];
    }
#pragma unroll
    for (int nf = 0; nf < 4; ++nf) {
      fbh[nf] = *(const bf16x8*)&bh[wn * 64 + nf * 16 + r16][g * 8];
      fbl[nf] = *(const bf16x8*)&bl[wn * 64 + nf * 16 + r16][g * 8];
    }
#pragma unroll
    for (int mf = 0; mf < 4; ++mf)
#pragma unroll
      for (int nf = 0; nf < 4; ++nf) {
        acc[mf][nf] = __builtin_amdgcn_mfma_f32_16x16x32_bf16(fah[mf], fbh[nf], acc[mf][nf], 0, 0, 0);
        acc[mf][nf] = __builtin_amdgcn_mfma_f32_16x16x32_bf16(fah[mf], fbl[nf], acc[mf][nf], 0, 0, 0);
        acc[mf][nf] = __builtin_amdgcn_mfma_f32_16x16x32_bf16(fal[mf], fbh[nf], acc[mf][nf], 0, 0, 0);
      }
    __syncthreads();
  }

  // ---- fused epilogue: s,t per row (this wave owns head `wn`, full 64 cols) ----
  const int head = wn;
  float asv[4], adv[4];
#pragma unroll
  for (int nf = 0; nf < 4; ++nf) {
    asv[nf] = a_src[head * 64 + nf * 16 + r16];
    adv[nf] = a_dst[head * 64 + nf * 16 + r16];
  }
#pragma unroll
  for (int mf = 0; mf < 4; ++mf) {
#pragma unroll
    for (int reg = 0; reg < 4; ++reg) {
      float sp = 0.f, tp = 0.f;
#pragma unroll
      for (int nf = 0; nf < 4; ++nf) {
        sp = fmaf(acc[mf][nf][reg], asv[nf], sp);
        tp = fmaf(acc[mf][nf][reg], adv[nf], tp);
      }
#pragma unroll
      for (int off = 1; off < 16; off <<= 1) {
        sp += __shfl_xor(sp, off);
        tp += __shfl_xor(tp, off);
      }
      int row = row0 + wm * 64 + mf * 16 + g * 4 + reg;
      if (r16 == 0 && row < n) {
        s_arr[row * 2 + head] = sp;
        t_arr[row * 2 + head] = tp;
      }
    }
  }

  // ---- f16 repack via LDS, coalesced store of h2h (interleaved heads) ----
  ushort_t* hstage = smem;  // [128][136], 272B row stride (16B aligned)
#pragma unroll
  for (int mf = 0; mf < 4; ++mf)
#pragma unroll
    for (int nf = 0; nf < 4; ++nf)
#pragma unroll
      for (int reg = 0; reg < 4; ++reg) {
        int rl = wm * 64 + mf * 16 + g * 4 + reg;
        int col = (nf * 16 + r16) * 2 + head;
        hstage[rl * 136 + col] = f2h_bits(acc[mf][nf][reg]);
      }
  __syncthreads();
#pragma unroll
  for (int it = 0; it < 8; ++it) {
    int idx = t + it * 256;
    int r = idx >> 4, ch = idx & 15;  // 16 chunks of 16B per 256B row
    if (row0 + r < n) {
      *(uint4*)((char*)h2h + (size_t)(row0 + r) * 256 + ch * 16) =
          *(const uint4*)&hstage[r * 136 + ch * 8];
    }
  }
}

// ---------------- MFMA GEMM + fused att1: h16(f16) + s,t; A[n,K]f32 @ W[K,64] ----------------
template <int K>
__global__ __launch_bounds__(256, 2) void gemm_mfma64_att_kernel(const float* __restrict__ A,
                                                                 const ushort_t* __restrict__ wth,
                                                                 const ushort_t* __restrict__ wtl,
                                                                 const float* __restrict__ a_src,
                                                                 const float* __restrict__ a_dst,
                                                                 __half* __restrict__ h16,
                                                                 float* __restrict__ s1,
                                                                 float* __restrict__ t1, int n) {
  __shared__ __align__(16) ushort_t smem[15360];
  ushort_t (*ah)[40] = (ushort_t(*)[40])smem;
  ushort_t (*al)[40] = (ushort_t(*)[40])(smem + 5120);
  ushort_t (*bh)[40] = (ushort_t(*)[40])(smem + 10240);
  ushort_t (*bl)[40] = (ushort_t(*)[40])(smem + 12800);

  const int t = threadIdx.x;
  const int row0 = blockIdx.x * 128;
  const int srow = t >> 1;
  const int skq = (t & 1) * 16;
  const int bcol = t >> 2;
  const int bkq = (t & 3) * 8;

  const int lane = t & 63;
  const int wid = t >> 6;
  const int r16 = lane & 15, g = lane >> 4;

  f32x4 acc[2][4];
#pragma unroll
  for (int i = 0; i < 2; ++i)
#pragma unroll
    for (int j = 0; j < 4; ++j) acc[i][j] = (f32x4)(0.f);

  for (int kt = 0; kt < K / 32; ++kt) {
    const int k0 = kt * 32;
    {
      uint_t hw[8], lw[8];
      if (row0 + srow < n) {
        const float* ap = &A[(size_t)(row0 + srow) * K + k0 + skq];
#pragma unroll
        for (int j = 0; j < 4; ++j) {
          float4 v = *(const float4*)(ap + j * 4);
          ushort_t h0 = f2bf_rn(v.x), h1 = f2bf_rn(v.y), h2 = f2bf_rn(v.z), h3 = f2bf_rn(v.w);
          ushort_t l0 = f2bf_rn(v.x - bf2f(h0)), l1 = f2bf_rn(v.y - bf2f(h1));
          ushort_t l2 = f2bf_rn(v.z - bf2f(h2)), l3 = f2bf_rn(v.w - bf2f(h3));
          hw[j * 2] = (uint_t)h0 | ((uint_t)h1 << 16);
          hw[j * 2 + 1] = (uint_t)h2 | ((uint_t)h3 << 16);
          lw[j * 2] = (uint_t)l0 | ((uint_t)l1 << 16);
          lw[j * 2 + 1] = (uint_t)l2 | ((uint_t)l3 << 16);
        }
      } else {
#pragma unroll
        for (int j = 0; j < 8; ++j) { hw[j] = 0; lw[j] = 0; }
      }
      *(uint4*)&ah[srow][skq] = make_uint4(hw[0], hw[1], hw[2], hw[3]);
      *(uint4*)&ah[srow][skq + 8] = make_uint4(hw[4], hw[5], hw[6], hw[7]);
      *(uint4*)&al[srow][skq] = make_uint4(lw[0], lw[1], lw[2], lw[3]);
      *(uint4*)&al[srow][skq + 8] = make_uint4(lw[4], lw[5], lw[6], lw[7]);
    }
    {
      uint4 vh = *(const uint4*)&wth[(size_t)bcol * K + k0 + bkq];
      uint4 vl = *(const uint4*)&wtl[(size_t)bcol * K + k0 + bkq];
      *(uint4*)&bh[bcol][bkq] = vh;
      *(uint4*)&bl[bcol][bkq] = vl;
    }
    __syncthreads();

    bf16x8 fah[2], fal[2], fbh[4], fbl[4];
#pragma unroll
    for (int mf = 0; mf < 2; ++mf) {
      fah[mf] = *(const bf16x8*)&ah[wid * 32 + mf * 16 + r16][g * 8];
      fal[mf] = *(const bf16x8*)&al[wid * 32 + mf * 16 + r16][g * 8];
    }
#pragma unroll
    for (int nf = 0; nf < 4; ++nf) {
      fbh[nf] = *(const bf16x8*)&bh[nf * 16 + r16][g * 8];
      fbl[nf] = *(const bf16x8*)&bl[nf * 16 + r16][g * 8];
    }
#pragma unroll
    for (int mf = 0; mf < 2; ++mf)
#pragma unroll
      for (int nf = 0; nf < 4; ++nf) {
        acc[mf][nf] = __builtin_amdgcn_mfma_f32_16x16x32_bf16(fah[mf], fbh[nf], acc[mf][nf], 0, 0, 0);
        acc[mf][nf] = __builtin_amdgcn_mfma_f32_16x16x32_bf16(fah[mf], fbl[nf], acc[mf][nf], 0, 0, 0);
        acc[mf][nf] = __builtin_amdgcn_mfma_f32_16x16x32_bf16(fal[mf], fbh[nf], acc[mf][nf], 0, 0, 0);
      }
    __syncthreads();
  }

  // ---- fused att1 epilogue (single head, wave owns full 64-col row) ----
  float asv[4], adv[4];
#pragma unroll
  for (int nf = 0; nf < 4; ++nf) {
    asv[nf] = a_src[nf * 16 + r16];
    adv[nf] = a_dst[nf * 16 + r16];
  }
#pragma unroll
  for (int mf = 0; mf < 2; ++mf) {
#pragma unroll
    for (int reg = 0; reg < 4; ++reg) {
      float sp = 0.f, tp = 0.f;
#pragma unroll
      for (int nf = 0; nf < 4; ++nf) {
        sp = fmaf(acc[mf][nf][reg], asv[nf], sp);
        tp = fmaf(acc[mf][nf][reg], adv[nf], tp);
      }
#pragma unroll
      for (int off = 1; off < 16; off <<= 1) {
        sp += __shfl_xor(sp, off);
        tp += __shfl_xor(tp, off);
      }
      int row = row0 + wid * 32 + mf * 16 + g * 4 + reg;
      if (r16 == 0 && row < n) {
        s1[row] = sp;
        t1[row] = tp;
      }
    }
  }

  // ---- f16 repack + coalesced store ----
  ushort_t* hstage = smem;  // [128][72], 144B row stride (16B aligned)
#pragma unroll
  for (int mf = 0; mf < 2; ++mf)
#pragma unroll
    for (int nf = 0; nf < 4; ++nf)
#pragma unroll
      for (int reg = 0; reg < 4; ++reg) {
        int rl = wid * 32 + mf * 16 + g * 4 + reg;
        int col = nf * 16 + r16;
        hstage[rl * 72 + col] = f2h_bits(acc[mf][nf][reg]);
      }
  __syncthreads();
#pragma unroll
  for (int it = 0; it < 4; ++it) {
    int idx = t + it * 256;
    int r = idx >> 3, ch = idx & 7;  // 8 chunks of 16B per 128B row
    if (row0 + r < n) {
      *(uint4*)((char*)h16 + (size_t)(row0 + r) * 128 + ch * 16) =
          *(const uint4*)&hstage[r * 72 + ch * 8];
    }
  }
}

// ---------------- MFMA GEMM: both MLP heads in one pass; W = [Wv|Wt] (128 cols), K=64 ----------------
__global__ __launch_bounds__(256, 2) void gemm_heads_kernel(const float* __restrict__ A,
                                                            const ushort_t* __restrict__ wth,
                                                            const ushort_t* __restrict__ wtl,
                                                            const float* __restrict__ bv,
                                                            const float* __restrict__ bt,
                                                            float* __restrict__ out_v,
                                                            float* __restrict__ out_t, int n) {
  constexpr int K = 64;
  __shared__ __align__(16) ushort_t smem[20480];
  ushort_t (*ah)[40] = (ushort_t(*)[40])smem;
  ushort_t (*al)[40] = (ushort_t(*)[40])(smem + 5120);
  ushort_t (*bh)[40] = (ushort_t(*)[40])(smem + 10240);
  ushort_t (*bl)[40] = (ushort_t(*)[40])(smem + 15360);

  const int t = threadIdx.x;
  const int row0 = blockIdx.x * 128;
  const int srow = t >> 1;
  const int skq = (t & 1) * 16;

  const int lane = t & 63;
  const int wid = t >> 6;
  const int wm = wid >> 1, wn = wid & 1;
  const int r16 = lane & 15, g = lane >> 4;

  f32x4 acc[4][4];
#pragma unroll
  for (int i = 0; i < 4; ++i)
#pragma unroll
    for (int j = 0; j < 4; ++j) acc[i][j] = (f32x4)(0.f);

  for (int kt = 0; kt < K / 32; ++kt) {
    const int k0 = kt * 32;
    {
      uint_t hw[8], lw[8];
      if (row0 + srow < n) {
        const float* ap = &A[(size_t)(row0 + srow) * K + k0 + skq];
#pragma unroll
        for (int j = 0; j < 4; ++j) {
          float4 v = *(const float4*)(ap + j * 4);
          ushort_t h0 = f2bf_rn(v.x), h1 = f2bf_rn(v.y), h2 = f2bf_rn(v.z), h3 = f2bf_rn(v.w);
          ushort_t l0 = f2bf_rn(v.x - bf2f(h0)), l1 = f2bf_rn(v.y - bf2f(h1));
          ushort_t l2 = f2bf_rn(v.z - bf2f(h2)), l3 = f2bf_rn(v.w - bf2f(h3));
          hw[j * 2] = (uint_t)h0 | ((uint_t)h1 << 16);
          hw[j * 2 + 1] = (uint_t)h2 | ((uint_t)h3 << 16);
          lw[j * 2] = (uint_t)l0 | ((uint_t)l1 << 16);
          lw[j * 2 + 1] = (uint_t)l2 | ((uint_t)l3 << 16);
        }
      } else {
#pragma unroll
        for (int j = 0; j < 8; ++j) { hw[j] = 0; lw[j] = 0; }
      }
      *(uint4*)&ah[srow][skq] = make_uint4(hw[0], hw[1], hw[2], hw[3]);
      *(uint4*)&ah[srow][skq + 8] = make_uint4(hw[4], hw[5], hw[6], hw[7]);
      *(uint4*)&al[srow][skq] = make_uint4(lw[0], lw[1], lw[2], lw[3]);
      *(uint4*)&al[srow][skq + 8] = make_uint4(lw[4], lw[5], lw[6], lw[7]);
    }
    {
      const ushort_t* ph = &wth[(size_t)srow * K + k0 + skq];
      const ushort_t* pl = &wtl[(size_t)srow * K + k0 + skq];
      uint4 vh0 = *(const uint4*)ph;
      uint4 vh1 = *(const uint4*)(ph + 8);
      uint4 vl0 = *(const uint4*)pl;
      uint4 vl1 = *(const uint4*)(pl + 8);
      *(uint4*)&bh[srow][skq] = vh0;
      *(uint4*)&bh[srow][skq + 8] = vh1;
      *(uint4*)&bl[srow][skq] = vl0;
      *(uint4*)&bl[srow][skq + 8] = vl1;
    }
    __syncthreads();

    bf16x8 fah[4], fal[4], fbh[4], fbl[4];
#pragma unroll
    for (int mf = 0; mf < 4; ++mf) {
      fah[mf] = *(const bf16x8*)&ah[wm * 64 + mf * 16 + r16][g * 8];
      fal[mf] = *(const bf16x8*)&al[wm * 64 + mf * 16 + r16][g * 8];
    }
#pragma unroll
    for (int nf = 0; nf < 4; ++nf) {
      fbh[nf] = *(const bf16x8*)&bh[wn * 64 + nf * 16 + r16][g * 8];
      fbl[nf] = *(const bf16x8*)&bl[wn * 64 + nf * 16 + r16][g * 8];
    }
#pragma unroll
    for (int mf = 0; mf < 4; ++mf)
#pragma unroll
      for (int nf = 0; nf < 4; ++nf) {
        acc[mf][nf] = __builtin_amdgcn_mfma_f32_16x16x32_bf16(fah[mf], fbh[nf], acc[mf][nf], 0, 0, 0);
        acc[mf][nf] = __builtin_amdgcn_mfma_f32_16x16x32_bf16(fah[mf], fbl[nf], acc[mf][nf], 0, 0, 0);
        acc[mf][nf] = __builtin_amdgcn_mfma_f32_16x16x32_bf16(fal[mf], fbh[nf], acc[mf][nf], 0, 0, 0);
      }
    __syncthreads();
  }

  const float* bias = wn ? bt : bv;
  float* outp = wn ? out_t : out_v;
#pragma unroll
  for (int mf = 0; mf < 4; ++mf) {
#pragma unroll
    for (int reg = 0; reg < 4; ++reg) {
      int row = row0 + wm * 64 + mf * 16 + g * 4 + reg;
      if (row < n) {
#pragma unroll
        for (int nf = 0; nf < 4; ++nf) {
          int c = nf * 16 + r16;
          float v = fmaxf(acc[mf][nf][reg] + bias[c], 0.f);
          outp[(size_t)row * 64 + c] = v;
        }
      }
    }
  }
}

// ---------------- two-pass softmax aggregation, H=2, f16 gathers ----------------
__global__ __launch_bounds__(256) void agg2_kernel(const __half2* __restrict__ h2h,
                                                   const float2* __restrict__ s2,
                                                   const float2* __restrict__ t2,
                                                   const int* __restrict__ row_ptr,
                                                   const int* __restrict__ col_src,
                                                   const float* __restrict__ bias,
                                                   float* __restrict__ out, int n, int do_relu) {
  int wid = (blockIdx.x * 256 + threadIdx.x) >> 6;
  int lane = threadIdx.x & 63;
  if (wid >= n) return;
  const int node = wid;
  const float2 tt = t2[node];
  const float t0 = tt.x, t1 = tt.y;
  const int beg = row_ptr[node], end = row_ptr[node + 1];

  float2 sself = s2[node];
  const float e_self0 = lrelu(sself.x + t0);
  const float e_self1 = lrelu(sself.y + t1);

  const int i_own = beg + lane;
  int src_own = node;
  float e0_own = -1e30f, e1_own = -1e30f;
  if (i_own < end) {
    src_own = col_src[i_own];
    float2 sv = s2[src_own];
    e0_own = lrelu(sv.x + t0);
    e1_own = lrelu(sv.y + t1);
  }
  float m0 = fmaxf(e_self0, e0_own), m1 = fmaxf(e_self1, e1_own);
  for (int i = beg + 64 + lane; i < end; i += 64) {
    float2 sv = s2[col_src[i]];
    m0 = fmaxf(m0, lrelu(sv.x + t0));
    m1 = fmaxf(m1, lrelu(sv.y + t1));
  }
#pragma unroll
  for (int off = 32; off > 0; off >>= 1) {
    m0 = fmaxf(m0, __shfl_xor(m0, off));
    m1 = fmaxf(m1, __shfl_xor(m1, off));
  }

  float p0 = __expf(e_self0 - m0);
  float p1 = __expf(e_self1 - m1);
  float d0 = p0, d1 = p1;
  float2 hself = __half22float2(h2h[(size_t)node * 64 + lane]);
  float acc0 = p0 * hself.x;
  float acc1 = p1 * hself.y;

  for (int base = beg; base < end; base += 64) {
    int srcn;
    float q0, q1;
    if (base == beg) {
      srcn = src_own;
      q0 = (i_own < end) ? __expf(e0_own - m0) : 0.f;
      q1 = (i_own < end) ? __expf(e1_own - m1) : 0.f;
    } else {
      int i = base + lane;
      srcn = node;
      q0 = 0.f; q1 = 0.f;
      if (i < end) {
        srcn = col_src[i];
        float2 sv = s2[srcn];
        q0 = __expf(lrelu(sv.x + t0) - m0);
        q1 = __expf(lrelu(sv.y + t1) - m1);
      }
    }
    const int cnt = min(64, end - base);
    const int cnt4 = (cnt + 3) & ~3;
    int i0 = __shfl(srcn, 0), i1 = __shfl(srcn, 1), i2 = __shfl(srcn, 2), i3 = __shfl(srcn, 3);
    __half2 b0 = h2h[(size_t)i0 * 64 + lane];
    __half2 b1 = h2h[(size_t)i1 * 64 + lane];
    __half2 b2 = h2h[(size_t)i2 * 64 + lane];
    __half2 b3 = h2h[(size_t)i3 * 64 + lane];
    for (int j = 0; j < cnt4; j += 4) {
      float p00 = __shfl(q0, j),     p01 = __shfl(q1, j);
      float p10 = __shfl(q0, j + 1), p11 = __shfl(q1, j + 1);
      float p20 = __shfl(q0, j + 2), p21 = __shfl(q1, j + 2);
      float p30 = __shfl(q0, j + 3), p31 = __shfl(q1, j + 3);
      __half2 c0 = b0, c1 = b1, c2 = b2, c3 = b3;
      if (j + 4 < cnt4) {
        int n0 = __shfl(srcn, j + 4), n1 = __shfl(srcn, j + 5);
        int n2 = __shfl(srcn, j + 6), n3 = __shfl(srcn, j + 7);
        b0 = h2h[(size_t)n0 * 64 + lane];
        b1 = h2h[(size_t)n1 * 64 + lane];
        b2 = h2h[(size_t)n2 * 64 + lane];
        b3 = h2h[(size_t)n3 * 64 + lane];
      }
      float2 f0 = __half22float2(c0), f1 = __half22float2(c1);
      float2 f2 = __half22float2(c2), f3 = __half22float2(c3);
      d0 += p00 + p10 + p20 + p30;
      d1 += p01 + p11 + p21 + p31;
      acc0 = fmaf(p00, f0.x, acc0);
      acc1 = fmaf(p01, f0.y, acc1);
      acc0 = fmaf(p10, f1.x, acc0);
      acc1 = fmaf(p11, f1.y, acc1);
      acc0 = fmaf(p20, f2.x, acc0);
      acc1 = fmaf(p21, f2.y, acc1);
      acc0 = fmaf(p30, f3.x, acc0);
      acc1 = fmaf(p31, f3.y, acc1);
    }
  }

  float o0 = acc0 / (d0 + 1e-16f) + bias[lane];
  float o1 = acc1 / (d1 + 1e-16f) + bias[64 + lane];
  if (do_relu) {
    o0 = fmaxf(o0, 0.f);
    o1 = fmaxf(o1, 0.f);
  }
  out[(size_t)node * 128 + lane] = o0;
  out[(size_t)node * 128 + 64 + lane] = o1;
}

// ---------------- two-pass softmax aggregation, H=1, f16 gathers ----------------
__global__ __launch_bounds__(256) void agg1_kernel(const __half* __restrict__ h16,
                                                   const float* __restrict__ s,
                                                   const float* __restrict__ t,
                                                   const int* __restrict__ row_ptr,
                                                   const int* __restrict__ col_src,
                                                   const float* __restrict__ bias,
                                                   float* __restrict__ out, int n) {
  int wid = (blockIdx.x * 256 + threadIdx.x) >> 6;
  int lane = threadIdx.x & 63;
  if (wid >= n) return;
  const int node = wid;
  const float t0 = t[node];
  const int beg = row_ptr[node], end = row_ptr[node + 1];

  const float e_self = lrelu(s[node] + t0);
  const int i_own = beg + lane;
  int src_own = node;
  float e_own = -1e30f;
  if (i_own < end) {
    src_own = col_src[i_own];
    e_own = lrelu(s[src_own] + t0);
  }
  float m0 = fmaxf(e_self, e_own);
  for (int i = beg + 64 + lane; i < end; i += 64) {
    m0 = fmaxf(m0, lrelu(s[col_src[i]] + t0));
  }
#pragma unroll
  for (int off = 32; off > 0; off >>= 1) m0 = fmaxf(m0, __shfl_xor(m0, off));

  float p = __expf(e_self - m0);
  float d0 = p;
  float acc0 = p * __half2float(h16[(size_t)node * 64 + lane]);

  for (int base = beg; base < end; base += 64) {
    int srcn;
    float q0;
    if (base == beg) {
      srcn = src_own;
      q0 = (i_own < end) ? __expf(e_own - m0) : 0.f;
    } else {
      int i = base + lane;
      srcn = node;
      q0 = 0.f;
      if (i < end) {
        srcn = col_src[i];
        q0 = __expf(lrelu(s[srcn] + t0) - m0);
      }
    }
    const int cnt = min(64, end - base);
    const int cnt4 = (cnt + 3) & ~3;
    int i0 = __shfl(srcn, 0), i1 = __shfl(srcn, 1), i2 = __shfl(srcn, 2), i3 = __shfl(srcn, 3);
    __half b0 = h16[(size_t)i0 * 64 + lane];
    __half b1 = h16[(size_t)i1 * 64 + lane];
    __half b2 = h16[(size_t)i2 * 64 + lane];
    __half b3 = h16[(size_t)i3 * 64 + lane];
    for (int j = 0; j < cnt4; j += 4) {
      float p0 = __shfl(q0, j),     p1 = __shfl(q0, j + 1);
      float p2 = __shfl(q0, j + 2), p3 = __shfl(q0, j + 3);
      float c0 = __half2float(b0), c1 = __half2float(b1);
      float c2 = __half2float(b2), c3 = __half2float(b3);
      if (j + 4 < cnt4) {
        int n0 = __shfl(srcn, j + 4), n1 = __shfl(srcn, j + 5);
        int n2 = __shfl(srcn, j + 6), n3 = __shfl(srcn, j + 7);
        b0 = h16[(size_t)n0 * 64 + lane];
        b1 = h16[(size_t)n1 * 64 + lane];
        b2 = h16[(size_t)n2 * 64 + lane];
        b3 = h16[(size_t)n3 * 64 + lane];
      }
      d0 += p0 + p1 + p2 + p3;
      acc0 = fmaf(p0, c0, acc0);
      acc0 = fmaf(p1, c1, acc0);
      acc0 = fmaf(p2, c2, acc0);
      acc0 = fmaf(p3, c3, acc0);
    }
  }
  out[(size_t)node * 64 + lane] = acc0 / (d0 + 1e-16f) + bias[lane];
}

extern "C" void kernel_launch(void* const* d_in, const int* in_sizes, int n_in,
                              void* d_out, int out_size, void* d_ws, size_t ws_size,
                              hipStream_t stream) {
  const float* x       = (const float*)d_in[0];
  const int*   ei      = (const int*)d_in[1];
  const float* W0      = (const float*)d_in[2];
  const float* a_src0  = (const float*)d_in[3];
  const float* a_dst0  = (const float*)d_in[4];
  const float* b0      = (const float*)d_in[5];
  const float* W1      = (const float*)d_in[6];
  const float* a_src1  = (const float*)d_in[7];
  const float* a_dst1  = (const float*)d_in[8];
  const float* b1      = (const float*)d_in[9];
  const float* W2      = (const float*)d_in[10];
  const float* a_src2  = (const float*)d_in[11];
  const float* a_dst2  = (const float*)d_in[12];
  const float* b2      = (const float*)d_in[13];
  const float* Wv      = (const float*)d_in[14];
  const float* bv      = (const float*)d_in[15];
  const float* Wt      = (const float*)d_in[16];
  const float* bt      = (const float*)d_in[17];

  const int n = NN, E = NE;
  const int NB = (n + 255) / 256;
  const int NBF = (n + 1 + 255) / 256;

  char* w = (char*)d_ws;
  int* counts  = (int*)w;   w += (size_t)n * 4;
  int* row_ptr = (int*)w;   w += (size_t)(n + 4) * 4;
  int* cursor  = (int*)w;   w += (size_t)n * 4;
  int* bsums   = (int*)w;   w += (size_t)256 * 4;
  int* col_src = (int*)w;   w += (size_t)E * 4;
  float* s_arr = (float*)w; w += (size_t)n * 2 * 4;
  float* t_arr = (float*)w; w += (size_t)n * 2 * 4;
  float* Abuf  = (float*)w;  w += (size_t)n * 128 * 4;   // 25.6 MB
  __half2* h2h = (__half2*)w; w += (size_t)n * 64 * 4;   // 12.8 MB
  __half* h16  = (__half*)w; w += (size_t)n * 64 * 2;    // 6.4 MB
  ushort_t* wt0h = (ushort_t*)w; w += (size_t)128 * 512 * 2;
  ushort_t* wt0l = (ushort_t*)w; w += (size_t)128 * 512 * 2;
  ushort_t* wt1h = (ushort_t*)w; w += (size_t)128 * 128 * 2;
  ushort_t* wt1l = (ushort_t*)w; w += (size_t)128 * 128 * 2;
  ushort_t* wt2h = (ushort_t*)w; w += (size_t)64 * 128 * 2;
  ushort_t* wt2l = (ushort_t*)w; w += (size_t)64 * 128 * 2;
  ushort_t* wHh  = (ushort_t*)w; w += (size_t)128 * 64 * 2;  // [Wv|Wt] concat, 128 cols x K=64
  ushort_t* wHl  = (ushort_t*)w; w += (size_t)128 * 64 * 2;

  float* s1 = s_arr;   // layer-2 reuses (float[n] fits in float[2n])
  float* t1 = t_arr;

  float* out_h = (float*)d_out;
  float* out_v = out_h + (size_t)n * 64;
  float* out_t = out_v + (size_t)n * 64;

  // ---- setup: memset + (count + all W preps) + scan + fill ----
  hipMemsetAsync(counts, 0, (size_t)n * 4, stream);
  setup_kernel<<<CNT_BLOCKS + 16 + 4 + 2 + 1 + 1, 256, 0, stream>>>(
      ei, counts, W0, wt0h, wt0l, W1, wt1h, wt1l, W2, wt2h, wt2l, Wv, Wt, wHh, wHl);
  scan_blocksum_kernel<<<NB, 256, 0, stream>>>(counts, bsums, n);
  scan_offsets_kernel<<<1, 256, 0, stream>>>(bsums, NB);
  scan_final_kernel<<<NBF, 256, 0, stream>>>(counts, bsums, row_ptr, cursor, n, E);
  fill_kernel<<<(E + 255) / 256, 256, 0, stream>>>(ei, row_ptr, cursor, col_src, E);

  const int wgrid = (n + 3) / 4;
  const int g128 = (n + 127) / 128;

  // ---- layer 0: x @ W0 -> h2h,s,t (fused) ; aggregate -> Abuf ----
  gemm_mfma_att_kernel<512><<<g128, 256, 0, stream>>>(x, wt0h, wt0l, a_src0, a_dst0,
                                                      h2h, s_arr, t_arr, n);
  agg2_kernel<<<wgrid, 256, 0, stream>>>(h2h, (const float2*)s_arr, (const float2*)t_arr,
                                         row_ptr, col_src, b0, Abuf, n, 1);

  // ---- layer 1: Abuf @ W1 -> h2h,s,t (fused) ; aggregate -> Abuf ----
  gemm_mfma_att_kernel<128><<<g128, 256, 0, stream>>>(Abuf, wt1h, wt1l, a_src1, a_dst1,
                                                      h2h, s_arr, t_arr, n);
  agg2_kernel<<<wgrid, 256, 0, stream>>>(h2h, (const float2*)s_arr, (const float2*)t_arr,
                                         row_ptr, col_src, b1, Abuf, n, 1);

  // ---- layer 2: Abuf @ W2 -> h16,s1,t1 (fused) ; aggregate -> out_h ----
  gemm_mfma64_att_kernel<128><<<g128, 256, 0, stream>>>(Abuf, wt2h, wt2l, a_src2, a_dst2,
                                                        h16, s1, t1, n);
  agg1_kernel<<<wgrid, 256, 0, stream>>>(h16, s1, t1, row_ptr, col_src, b2, out_h, n);

  // ---- both MLP heads in one GEMM ----
  gemm_heads_kernel<<<g128, 256, 0, stream>>>(out_h, wHh, wHl, bv, bt, out_v, out_t, n);
}